// Round 7
// baseline (44688.461 us; speedup 1.0000x reference)
//
#include <hip/hip_runtime.h>
#include <hip/hip_cooperative_groups.h>
#include <climits>

namespace cg = cooperative_groups;

static constexpr int G    = 100;
static constexpr int G3   = G * G * G;
static constexpr int NSUB   = 600;     // 20 frames x 30 substeps
static constexpr int SPF    = 30;      // substeps per frame
static constexpr int NSTEPS = 20;      // frames
static constexpr int NTHR   = 512;     // 8 waves/block
static constexpr int NBLK   = 108;     // worker blocks: 6x3x6 bricks of 5x5x5 particles
static constexpr int TCIN   = 2048;    // LDS IN-tile capacity (float4/cell = 32 KB)
static constexpr int TCOUT  = 2048;    // LDS OUT-tile / private-tile capacity (cells)

__device__ __forceinline__ int clampi(int v) {
    return v < 0 ? 0 : (v > G - 1 ? G - 1 : v);
}
__device__ __forceinline__ int maxi(int a, int b) { return a > b ? a : b; }
__device__ __forceinline__ int mini(int a, int b) { return a < b ? a : b; }

// MALL-coherent (agent-scope, relaxed) helpers. ALL cross-block data goes
// through these or agent-scope atomics -> never cached dirty in any L2 ->
// grid barriers need no cache maintenance.
__device__ __forceinline__ float4 cell_load(const float4* p) {
    const unsigned long long* q = reinterpret_cast<const unsigned long long*>(p);
    unsigned long long a = __hip_atomic_load(&q[0], __ATOMIC_RELAXED, __HIP_MEMORY_SCOPE_AGENT);
    unsigned long long b = __hip_atomic_load(&q[1], __ATOMIC_RELAXED, __HIP_MEMORY_SCOPE_AGENT);
    float4 r;
    r.x = __uint_as_float((unsigned)(a & 0xffffffffu));
    r.y = __uint_as_float((unsigned)(a >> 32));
    r.z = __uint_as_float((unsigned)(b & 0xffffffffu));
    r.w = __uint_as_float((unsigned)(b >> 32));
    return r;
}
__device__ __forceinline__ void cell_store(float4* p, float x, float y, float z, float w) {
    unsigned long long* q = reinterpret_cast<unsigned long long*>(p);
    unsigned long long a = ((unsigned long long)__float_as_uint(y) << 32) | __float_as_uint(x);
    unsigned long long b = ((unsigned long long)__float_as_uint(w) << 32) | __float_as_uint(z);
    __hip_atomic_store(&q[0], a, __ATOMIC_RELAXED, __HIP_MEMORY_SCOPE_AGENT);
    __hip_atomic_store(&q[1], b, __ATOMIC_RELAXED, __HIP_MEMORY_SCOPE_AGENT);
}
__device__ __forceinline__ int iload(const int* p) {
    return __hip_atomic_load(p, __ATOMIC_RELAXED, __HIP_MEMORY_SCOPE_AGENT);
}
__device__ __forceinline__ void istore(int* p, int v) {
    __hip_atomic_store(p, v, __ATOMIC_RELAXED, __HIP_MEMORY_SCOPE_AGENT);
}
__device__ __forceinline__ void fstore(float* p, float v) {
    __hip_atomic_store(p, v, __ATOMIC_RELAXED, __HIP_MEMORY_SCOPE_AGENT);
}

// LDS-visibility-only block barrier. sched_barrier(0) per rule #18.
__device__ __forceinline__ void bar_lds() {
    __builtin_amdgcn_sched_barrier(0);
    asm volatile("s_waitcnt lgkmcnt(0)" ::: "memory");
    __builtin_amdgcn_s_barrier();
    __builtin_amdgcn_sched_barrier(0);
}

// Grid barrier: __syncthreads drains each wave's vmcnt (publishes all prior
// agent stores), thread 0 is the sole global arriver/poller, LDS-flag
// broadcast to the other waves. gen = 1-based count of this barrier call;
// all blocks execute an identical barrier sequence.
__device__ __forceinline__ void gridbar(unsigned* cnt, unsigned* flag,
                                        unsigned* lflag, unsigned gen) {
    __syncthreads();
    if (threadIdx.x == 0) {
        const unsigned old = __hip_atomic_fetch_add(cnt, 1u, __ATOMIC_RELAXED, __HIP_MEMORY_SCOPE_AGENT);
        if (old == gen * (unsigned)NBLK - 1u) {
            __hip_atomic_store(flag, gen, __ATOMIC_RELEASE, __HIP_MEMORY_SCOPE_AGENT);
        }
        while (__hip_atomic_load(flag, __ATOMIC_RELAXED, __HIP_MEMORY_SCOPE_AGENT) < gen) { }
        __hip_atomic_store(lflag, gen, __ATOMIC_RELAXED, __HIP_MEMORY_SCOPE_WORKGROUP);
    }
    while (__hip_atomic_load(lflag, __ATOMIC_RELAXED, __HIP_MEMORY_SCOPE_WORKGROUP) < gen) { }
    asm volatile("" ::: "memory");
}

// Persistent cooperative kernel.
// ROUND-7: producer tiles + ONE owner-reduction pass (fixes r6's consumer-
// side read multiplication while keeping shared-grid atomics eliminated;
// r5 measured slice-serialized RMW ~2.7ns -> old flush 8-15us/substep).
//   ws: priv[NBLK][TCOUT] float4 | redg[G3] float4 | meta[NBLK][8] int
// Per substep:
//   [A]  stage own p-1 true-bbox from redg (1 load/cell, norm+BC) -> tileIn
//   [S1] G2P + physics + LDS scatter into grown tile
//   [C1] plain coalesced stores: LDS tile -> priv[block]; publish bbox meta
//   -- gridbar #1 --
//   [C2] owner pass: union bbox flat-partitioned over blocks; each owned
//        cell sums covering tiles once -> plain store redg (and, at frame
//        end, out = vs + mass; out pre-filled with vs at init)
//   -- gridbar #2 -- (skipped after the last substep; kernel-end releases)
// redg/priv/meta single-buffered: reads and writes are on opposite sides of
// gridbar #1/#2 in every substep. No zeroing anywhere (full-tile overwrite;
// readers stay inside published bboxes).
// Oversized-tile fallback (~never): meta.ovf=1; all blocks see uniform
// anyOvf -> one extra uniform gridbar, then the ovf block atomic-adds its
// particles onto the owner-initialized redg (+ out mass at frame end).
__launch_bounds__(NTHR)
__global__ void mpm_sim(const float* __restrict__ vscal,
                        const float* __restrict__ q0,
                        const float* __restrict__ qd0,
                        float* __restrict__ out,
                        float* __restrict__ ws,
                        unsigned* __restrict__ barcnt,
                        unsigned* __restrict__ barflag)
{
    const float vs = vscal[0];
    float4* const priv  = reinterpret_cast<float4*>(ws);         // [NBLK][TCOUT]
    float4* const redg  = priv + NBLK * TCOUT;                   // [G3]
    int*    const metaG = reinterpret_cast<int*>(redg + G3);     // [NBLK][8]

    cg::grid_group gg = cg::this_grid();
    const int tid = blockIdx.x * NTHR + threadIdx.x;
    const int nth = NBLK * NTHR;

    __shared__ float4 tileIn[TCIN];        // normalized grid velocity per cell
    __shared__ float  tileOut[4 * TCOUT];  // scatter accum: [mx,my,mz,mass]
    __shared__ int    metaL[NBLK][8];      // substep metas (owner pass)
    __shared__ int    sred[6];             // true-bbox reduction
    __shared__ int    ured[6];             // union bbox (owner pass)
    __shared__ int    anyOvfS;
    __shared__ unsigned lflag;             // LDS broadcast of barrier gen

    // ---- init: vs-fill ALL out slabs, reset barrier lines ----
    {
        float4* o4 = reinterpret_cast<float4*>(out);
        const float4 vf = make_float4(vs, vs, vs, vs);
        const int on4 = NSTEPS * G3 / 4;
        for (int i = tid; i < on4; i += nth) o4[i] = vf;
        if (tid == 0) {
            __hip_atomic_store(barcnt,  0u, __ATOMIC_RELAXED, __HIP_MEMORY_SCOPE_AGENT);
            __hip_atomic_store(barflag, 0u, __ATOMIC_RELAXED, __HIP_MEMORY_SCOPE_AGENT);
        }
        if (threadIdx.x == 0) lflag = 0u;
    }

    gg.sync();   // publish init before first phase

    // brick/slot -> original particle index (4 lanes per particle)
    const int slot = threadIdx.x >> 2;
    const int sub  = threadIdx.x & 3;
    const bool act = slot < 125;
    int pid = 0;
    if (act) {
        const int b  = blockIdx.x;
        const int bx = b / 18;
        const int by = (b / 6) % 3;
        const int bz = b % 6;
        const int lx = slot / 25;
        const int rem = slot % 25;
        const int ly = rem / 5;
        const int lz = rem % 5;
        pid = ((bx * 5 + lx) * 15 + (by * 5 + ly)) * 30 + (bz * 5 + lz);
    }

    const float DT      = 5e-4f;
    const float INV_DX  = 100.0f;
    const float DXc     = 0.01f;
    const float MU      = (float)(1.0e5 / (2.0 * (1.0 + 0.3)));
    const float LAM     = (float)(1.0e5 * 0.3 / ((1.0 + 0.3) * (1.0 - 0.6)));
    const float P_MASS  = (float)(0.005 * 0.005 * 0.005 * 3000.0);
    const float KS      = (float)(-5.0e-4 * (0.005 * 0.005 * 0.005) * 4.0 * 100.0 * 100.0);
    const float DTG     = (float)(5.0e-4 * (-9.8));
    const float CSC     = 4.0f * INV_DX * INV_DX;

    float px = 0.f, py = 0.f, pz = 0.f, vx = 0.f, vy = 0.f, vz = 0.f;
    float C00 = 0.f, C01 = 0.f, C02 = 0.f,
          C10 = 0.f, C11 = 0.f, C12 = 0.f,
          C20 = 0.f, C21 = 0.f, C22 = 0.f;
    float F00 = 1.f, F01 = 0.f, F02 = 0.f,
          F10 = 0.f, F11 = 1.f, F12 = 0.f,
          F20 = 0.f, F21 = 0.f, F22 = 1.f;
    if (act) {
        px = q0[3 * pid + 0]; py = q0[3 * pid + 1]; pz = q0[3 * pid + 2];
        vx = qd0[3 * pid + 0]; vy = qd0[3 * pid + 1]; vz = qd0[3 * pid + 2];
    }

    // TRUE scatter-bbox history (uniform across wg)
    int pmn0 = 0, pmn1 = 0, pmn2 = 0, pmx0 = -1, pmx1 = -1, pmx2 = -1; bool pvalid = false;

    unsigned gen = 0;

    for (int p = 0; p < NSUB; ++p) {
        const int fc = p % SPF;
        float* const outF = (fc == SPF - 1) ? (out + (p / SPF) * G3) : nullptr;

        // grown scatter tile = prev true bbox +1 cell each side (fast path;
        // per-substep motion < 0.15 cells, so no bbox sync needed)
        const int tmn0 = pvalid ? maxi(pmn0 - 1, 0) : 0;
        const int tmn1 = pvalid ? maxi(pmn1 - 1, 0) : 0;
        const int tmn2 = pvalid ? maxi(pmn2 - 1, 0) : 0;
        const int tD0  = pvalid ? (mini(pmx0 + 1, G - 1) - tmn0 + 1) : 0;
        const int tD1  = pvalid ? (mini(pmx1 + 1, G - 1) - tmn1 + 1) : 0;
        const int tD2  = pvalid ? (mini(pmx2 + 1, G - 1) - tmn2 + 1) : 0;
        const int tvol = pvalid ? tD0 * tD1 * tD2 : 0;
        const bool fast = pvalid && (tvol <= TCOUT);

        // ---------- [A] staging from reduced grid (like the r2 baseline) ----------
        if (threadIdx.x == 0) {
            sred[0] = INT_MAX; sred[1] = INT_MAX; sred[2] = INT_MAX;
            sred[3] = INT_MIN; sred[4] = INT_MIN; sred[5] = INT_MIN;
        }
        const int iD1 = pvalid ? (pmx1 - pmn1 + 1) : 0;
        const int iD2 = pvalid ? (pmx2 - pmn2 + 1) : 0;
        const int inVol = pvalid ? (pmx0 - pmn0 + 1) * iD1 * iD2 : 0;
        const bool staged = pvalid && (inVol <= TCIN);
        if (staged && p > 0) {
            for (int c = threadIdx.x; c < inVol; c += NTHR) {
                const int k = c % iD2;
                const int t = c / iD2;
                const int j = t % iD1;
                const int i = t / iD1;
                const int nx = pmn0 + i, ny = pmn1 + j, nz = pmn2 + k;
                const float4 gq = cell_load(&redg[(nx * G + ny) * G + nz]);
                const float den = gq.w + vs;
                float gvx = gq.x / den;
                float gvy = gq.y / den;
                float gvz = gq.z / den;
                if (nx < 3       && gvx < 0.f) gvx = 0.f;
                if (nx >= G - 3  && gvx > 0.f) gvx = 0.f;
                if (ny < 3       && gvy < 0.f) gvy = 0.f;
                if (ny >= G - 3  && gvy > 0.f) gvy = 0.f;
                if (nz < 3       && gvz < 0.f) gvz = 0.f;
                if (nz >= G - 3  && gvz > 0.f) gvz = 0.f;
                tileIn[c] = make_float4(gvx, gvy, gvz, 0.f);
            }
        }
        // tileOut zero (grown tile in fast path, full capacity in fallback)
        {
            float4* t4 = reinterpret_cast<float4*>(tileOut);
            const float4 z = make_float4(0.f, 0.f, 0.f, 0.f);
            const int zn = fast ? tvol : TCOUT;
            for (int i = threadIdx.x; i < zn; i += NTHR) t4[i] = z;
        }
        bar_lds();   // S1

        int sb0 = 0, sb1 = 0, sb2 = 0;
        float fx0 = 0.f, fx1 = 0.f, fx2 = 0.f;
        float A00 = 0.f, A01 = 0.f, A02 = 0.f,
              A10 = 0.f, A11 = 0.f, A12 = 0.f,
              A20 = 0.f, A21 = 0.f, A22 = 0.f;
        float mvx = 0.f, mvy = 0.f, mvz = 0.f;

        if (act) {
            // ======== G2P gather for substep p-1 ========
            if (p > 0) {
                const float xs0 = px * INV_DX, xs1 = py * INV_DX, xs2 = pz * INV_DX;
                const float fb0 = floorf(xs0 - 0.5f), fb1 = floorf(xs1 - 0.5f), fb2 = floorf(xs2 - 0.5f);
                const int b0 = (int)fb0, b1 = (int)fb1, b2 = (int)fb2;
                const float gx0 = xs0 - fb0, gx1 = xs1 - fb1, gx2 = xs2 - fb2;
                float wa[3], wb[3], wc[3];
                wa[0] = 0.5f * (1.5f - gx0) * (1.5f - gx0);
                wa[1] = 0.75f - (gx0 - 1.0f) * (gx0 - 1.0f);
                wa[2] = 0.5f * (gx0 - 0.5f) * (gx0 - 0.5f);
                wb[0] = 0.5f * (1.5f - gx1) * (1.5f - gx1);
                wb[1] = 0.75f - (gx1 - 1.0f) * (gx1 - 1.0f);
                wb[2] = 0.5f * (gx1 - 0.5f) * (gx1 - 0.5f);
                wc[0] = 0.5f * (1.5f - gx2) * (1.5f - gx2);
                wc[1] = 0.75f - (gx2 - 1.0f) * (gx2 - 1.0f);
                wc[2] = 0.5f * (gx2 - 0.5f) * (gx2 - 0.5f);

                float nvx = 0.f, nvy = 0.f, nvz = 0.f;
                float nc00 = 0.f, nc01 = 0.f, nc02 = 0.f,
                      nc10 = 0.f, nc11 = 0.f, nc12 = 0.f,
                      nc20 = 0.f, nc21 = 0.f, nc22 = 0.f;
                #pragma unroll
                for (int t = 0; t < 7; ++t) {
                    const int c = sub + 4 * t;
                    if (c >= 27) break;
                    const int oi = c / 9;
                    const int rem = c - 9 * oi;
                    const int oj = rem / 3;
                    const int ok = rem - 3 * oj;
                    const int nx = clampi(b0 + oi);
                    const int ny = clampi(b1 + oj);
                    const int nz = clampi(b2 + ok);
                    const float dpx = ((float)oi - gx0) * DXc;
                    const float dpy = ((float)oj - gx1) * DXc;
                    const float dpz = ((float)ok - gx2) * DXc;
                    const float w = wa[oi] * wb[oj] * wc[ok];
                    float gvx, gvy, gvz;
                    if (staged) {
                        const float4 gv4 = tileIn[((nx - pmn0) * iD1 + (ny - pmn1)) * iD2 + (nz - pmn2)];
                        gvx = gv4.x; gvy = gv4.y; gvz = gv4.z;
                    } else {
                        const float4 gq = cell_load(&redg[(nx * G + ny) * G + nz]);
                        const float den = gq.w + vs;
                        gvx = gq.x / den;
                        gvy = gq.y / den;
                        gvz = gq.z / den;
                        if (nx < 3       && gvx < 0.f) gvx = 0.f;
                        if (nx >= G - 3  && gvx > 0.f) gvx = 0.f;
                        if (ny < 3       && gvy < 0.f) gvy = 0.f;
                        if (ny >= G - 3  && gvy > 0.f) gvy = 0.f;
                        if (nz < 3       && gvz < 0.f) gvz = 0.f;
                        if (nz >= G - 3  && gvz > 0.f) gvz = 0.f;
                    }
                    nvx += w * gvx; nvy += w * gvy; nvz += w * gvz;
                    const float wgx = w * gvx, wgy = w * gvy, wgz = w * gvz;
                    nc00 += wgx * dpx; nc01 += wgx * dpy; nc02 += wgx * dpz;
                    nc10 += wgy * dpx; nc11 += wgy * dpy; nc12 += wgy * dpz;
                    nc20 += wgz * dpx; nc21 += wgz * dpy; nc22 += wgz * dpz;
                }
                #define BFLY(v) { v += __shfl_xor(v, 1); v += __shfl_xor(v, 2); }
                BFLY(nvx) BFLY(nvy) BFLY(nvz)
                BFLY(nc00) BFLY(nc01) BFLY(nc02)
                BFLY(nc10) BFLY(nc11) BFLY(nc12)
                BFLY(nc20) BFLY(nc21) BFLY(nc22)
                #undef BFLY
                vx = nvx; vy = nvy; vz = nvz;
                C00 = CSC * nc00; C01 = CSC * nc01; C02 = CSC * nc02;
                C10 = CSC * nc10; C11 = CSC * nc11; C12 = CSC * nc12;
                C20 = CSC * nc20; C21 = CSC * nc21; C22 = CSC * nc22;
                px += DT * vx; py += DT * vy; pz += DT * vz;
            }

            // ======== F update ========
            {
                const float t00 = F00 + DT * (C00 * F00 + C01 * F10 + C02 * F20);
                const float t01 = F01 + DT * (C00 * F01 + C01 * F11 + C02 * F21);
                const float t02 = F02 + DT * (C00 * F02 + C01 * F12 + C02 * F22);
                const float t10 = F10 + DT * (C10 * F00 + C11 * F10 + C12 * F20);
                const float t11 = F11 + DT * (C10 * F01 + C11 * F11 + C12 * F21);
                const float t12 = F12 + DT * (C10 * F02 + C11 * F12 + C12 * F22);
                const float t20 = F20 + DT * (C20 * F00 + C21 * F10 + C22 * F20);
                const float t21 = F21 + DT * (C20 * F01 + C21 * F11 + C22 * F21);
                const float t22 = F22 + DT * (C20 * F02 + C21 * F12 + C22 * F22);
                F00 = t00; F01 = t01; F02 = t02;
                F10 = t10; F11 = t11; F12 = t12;
                F20 = t20; F21 = t21; F22 = t22;
            }

            // ======== neo-Hookean PK1 -> affine ========
            const float c00 = F11 * F22 - F12 * F21;
            const float c01 = F12 * F20 - F10 * F22;
            const float c02 = F10 * F21 - F11 * F20;
            const float det = F00 * c00 + F01 * c01 + F02 * c02;
            const float c10 = F02 * F21 - F01 * F22;
            const float c11 = F00 * F22 - F02 * F20;
            const float c12 = F01 * F20 - F00 * F21;
            const float c20 = F01 * F12 - F02 * F11;
            const float c21 = F02 * F10 - F00 * F12;
            const float c22 = F00 * F11 - F01 * F10;
            const float idet = 1.0f / det;
            const float lj = LAM * logf(fmaxf(det, 1e-6f));
            const float fit00 = c00 * idet, fit01 = c01 * idet, fit02 = c02 * idet;
            const float fit10 = c10 * idet, fit11 = c11 * idet, fit12 = c12 * idet;
            const float fit20 = c20 * idet, fit21 = c21 * idet, fit22 = c22 * idet;
            const float P00 = MU * (F00 - fit00) + lj * fit00;
            const float P01 = MU * (F01 - fit01) + lj * fit01;
            const float P02 = MU * (F02 - fit02) + lj * fit02;
            const float P10 = MU * (F10 - fit10) + lj * fit10;
            const float P11 = MU * (F11 - fit11) + lj * fit11;
            const float P12 = MU * (F12 - fit12) + lj * fit12;
            const float P20 = MU * (F20 - fit20) + lj * fit20;
            const float P21 = MU * (F21 - fit21) + lj * fit21;
            const float P22 = MU * (F22 - fit22) + lj * fit22;
            A00 = KS * (P00 * F00 + P01 * F01 + P02 * F02) + P_MASS * C00;
            A01 = KS * (P00 * F10 + P01 * F11 + P02 * F12) + P_MASS * C01;
            A02 = KS * (P00 * F20 + P01 * F21 + P02 * F22) + P_MASS * C02;
            A10 = KS * (P10 * F00 + P11 * F01 + P12 * F02) + P_MASS * C10;
            A11 = KS * (P10 * F10 + P11 * F11 + P12 * F12) + P_MASS * C11;
            A12 = KS * (P10 * F20 + P11 * F21 + P12 * F22) + P_MASS * C12;
            A20 = KS * (P20 * F00 + P21 * F01 + P22 * F02) + P_MASS * C20;
            A21 = KS * (P20 * F10 + P21 * F11 + P22 * F12) + P_MASS * C21;
            A22 = KS * (P20 * F20 + P21 * F21 + P22 * F22) + P_MASS * C22;

            const float xs0 = px * INV_DX, xs1 = py * INV_DX, xs2 = pz * INV_DX;
            const float fb0 = floorf(xs0 - 0.5f), fb1 = floorf(xs1 - 0.5f), fb2 = floorf(xs2 - 0.5f);
            sb0 = (int)fb0; sb1 = (int)fb1; sb2 = (int)fb2;
            fx0 = xs0 - fb0; fx1 = xs1 - fb1; fx2 = xs2 - fb2;
            mvx = P_MASS * vx;
            mvy = P_MASS * (vy + DTG);
            mvz = P_MASS * vz;

            if (sub == 0) {   // true-bbox reduction (read after S2/S3)
                atomicMin(&sred[0], clampi(sb0)); atomicMax(&sred[3], clampi(sb0 + 2));
                atomicMin(&sred[1], clampi(sb1)); atomicMax(&sred[4], clampi(sb1 + 2));
                atomicMin(&sred[2], clampi(sb2)); atomicMax(&sred[5], clampi(sb2 + 2));
            }
        }

        float wa0 = 0.f, wa1 = 0.f, wa2 = 0.f, wb0 = 0.f, wb1 = 0.f, wb2 = 0.f,
              wcc0 = 0.f, wcc1 = 0.f, wcc2 = 0.f;
        if (act) {
            wa0 = 0.5f * (1.5f - fx0) * (1.5f - fx0);
            wa1 = 0.75f - (fx0 - 1.0f) * (fx0 - 1.0f);
            wa2 = 0.5f * (fx0 - 0.5f) * (fx0 - 0.5f);
            wb0 = 0.5f * (1.5f - fx1) * (1.5f - fx1);
            wb1 = 0.75f - (fx1 - 1.0f) * (fx1 - 1.0f);
            wb2 = 0.5f * (fx1 - 0.5f) * (fx1 - 0.5f);
            wcc0 = 0.5f * (1.5f - fx2) * (1.5f - fx2);
            wcc1 = 0.75f - (fx2 - 1.0f) * (fx2 - 1.0f);
            wcc2 = 0.5f * (fx2 - 0.5f) * (fx2 - 0.5f);
        }
        const float WA[3] = { wa0, wa1, wa2 };
        const float WB[3] = { wb0, wb1, wb2 };
        const float WC[3] = { wcc0, wcc1, wcc2 };

        bool myOvf = false;
        int fm0 = tmn0, fm1 = tmn1, fm2 = tmn2, fD0 = tD0, fD1 = tD1, fD2 = tD2, fvol = tvol;

        if (fast) {
            // ======== scatter into grown tile ========
            if (act) {
                #pragma unroll
                for (int t = 0; t < 7; ++t) {
                    const int c = sub + 4 * t;
                    if (c >= 27) break;
                    const int oi = c / 9;
                    const int rem = c - 9 * oi;
                    const int oj = rem / 3;
                    const int ok = rem - 3 * oj;
                    const int li  = clampi(sb0 + oi) - tmn0;
                    const int lj2 = clampi(sb1 + oj) - tmn1;
                    const int lk  = clampi(sb2 + ok) - tmn2;
                    const float dpx = ((float)oi - fx0) * DXc;
                    const float dpy = ((float)oj - fx1) * DXc;
                    const float dpz = ((float)ok - fx2) * DXc;
                    const float w = WA[oi] * WB[oj] * WC[ok];
                    const int c4 = 4 * ((li * tD1 + lj2) * tD2 + lk);
                    atomicAdd(&tileOut[c4 + 0], w * (mvx + A00 * dpx + A01 * dpy + A02 * dpz));
                    atomicAdd(&tileOut[c4 + 1], w * (mvy + A10 * dpx + A11 * dpy + A12 * dpz));
                    atomicAdd(&tileOut[c4 + 2], w * (mvz + A20 * dpx + A21 * dpy + A22 * dpz));
                    atomicAdd(&tileOut[c4 + 3], w * P_MASS);
                }
            }
            bar_lds();   // S3
            // [C1] plain coalesced stores: full grown tile -> private buffer
            for (int c = threadIdx.x; c < tvol; c += NTHR)
                cell_store(&priv[blockIdx.x * TCOUT + c],
                           tileOut[4 * c + 0], tileOut[4 * c + 1],
                           tileOut[4 * c + 2], tileOut[4 * c + 3]);
        } else {
            // ======== fallback: bbox-sync path (p==0 or oversized tile) ========
            bar_lds();   // S2: bbox ready
            const int mn0 = sred[0], mn1 = sred[1], mn2 = sred[2];
            const int mx0 = sred[3], mx1 = sred[4], mx2 = sred[5];
            const int D1 = mx1 - mn1 + 1, D2 = mx2 - mn2 + 1, D0 = mx0 - mn0 + 1;
            const int vol = (mx0 >= mn0) ? D0 * D1 * D2 : 0;
            fm0 = mn0; fm1 = mn1; fm2 = mn2; fD0 = D0; fD1 = D1; fD2 = D2; fvol = vol;
            if (vol > 0 && vol <= TCOUT) {
                if (act) {
                    #pragma unroll
                    for (int t = 0; t < 7; ++t) {
                        const int c = sub + 4 * t;
                        if (c >= 27) break;
                        const int oi = c / 9;
                        const int rem = c - 9 * oi;
                        const int oj = rem / 3;
                        const int ok = rem - 3 * oj;
                        const int li  = clampi(sb0 + oi) - mn0;
                        const int lj2 = clampi(sb1 + oj) - mn1;
                        const int lk  = clampi(sb2 + ok) - mn2;
                        const float dpx = ((float)oi - fx0) * DXc;
                        const float dpy = ((float)oj - fx1) * DXc;
                        const float dpz = ((float)ok - fx2) * DXc;
                        const float w = WA[oi] * WB[oj] * WC[ok];
                        const int c4 = 4 * ((li * D1 + lj2) * D2 + lk);
                        atomicAdd(&tileOut[c4 + 0], w * (mvx + A00 * dpx + A01 * dpy + A02 * dpz));
                        atomicAdd(&tileOut[c4 + 1], w * (mvy + A10 * dpx + A11 * dpy + A12 * dpz));
                        atomicAdd(&tileOut[c4 + 2], w * (mvz + A20 * dpx + A21 * dpy + A22 * dpz));
                        atomicAdd(&tileOut[c4 + 3], w * P_MASS);
                    }
                }
                bar_lds();   // S3
                for (int c = threadIdx.x; c < vol; c += NTHR)
                    cell_store(&priv[blockIdx.x * TCOUT + c],
                               tileOut[4 * c + 0], tileOut[4 * c + 1],
                               tileOut[4 * c + 2], tileOut[4 * c + 3]);
            } else {
                myOvf = (vol > 0);
                bar_lds();   // S3 (uniform)
            }
        }

        // publish meta (own cache line region; before gridbar #1)
        if (threadIdx.x == 0) {
            int* m = metaG + blockIdx.x * 8;
            istore(&m[0], fm0); istore(&m[1], fm1); istore(&m[2], fm2);
            istore(&m[3], (fvol > 0) ? fD0 : 0);
            istore(&m[4], fD1); istore(&m[5], fD2);
            istore(&m[6], myOvf ? 1 : 0);
        }

        // shift TRUE bbox history (sred valid after S2/S3)
        pmn0 = sred[0]; pmn1 = sred[1]; pmn2 = sred[2];
        pmx0 = sred[3]; pmx1 = sred[4]; pmx2 = sred[5]; pvalid = (pmx0 >= pmn0);

        gridbar(barcnt, barflag, &lflag, ++gen);   // #1: tiles + metas visible

        // ---------- [C2] owner-reduction pass ----------
        if (threadIdx.x == 0) {
            anyOvfS = 0;
            ured[0] = INT_MAX; ured[1] = INT_MAX; ured[2] = INT_MAX;
            ured[3] = INT_MIN; ured[4] = INT_MIN; ured[5] = INT_MIN;
        }
        for (int i = threadIdx.x; i < NBLK * 8; i += NTHR)
            (&metaL[0][0])[i] = iload(&metaG[i]);
        bar_lds();   // metaL + resets visible
        if (threadIdx.x < NBLK) {
            const int b = threadIdx.x;
            if (metaL[b][3] > 0) {
                if (metaL[b][6]) atomicOr(&anyOvfS, 1);
                atomicMin(&ured[0], metaL[b][0]); atomicMax(&ured[3], metaL[b][0] + metaL[b][3] - 1);
                atomicMin(&ured[1], metaL[b][1]); atomicMax(&ured[4], metaL[b][1] + metaL[b][4] - 1);
                atomicMin(&ured[2], metaL[b][2]); atomicMax(&ured[5], metaL[b][2] + metaL[b][5] - 1);
            }
        }
        bar_lds();   // union + anyOvf ready
        const int anyOvf = anyOvfS;
        if (ured[3] >= ured[0]) {
            const int u0 = ured[0], u1 = ured[1], u2 = ured[2];
            const int uD0 = ured[3] - u0 + 1, uD1 = ured[4] - u1 + 1, uD2 = ured[5] - u2 + 1;
            const int vol = uD0 * uD1 * uD2;
            const int per = (vol + NBLK - 1) / NBLK;
            const int beg = (int)blockIdx.x * per;
            const int end = mini(beg + per, vol);
            for (int c = beg + (int)threadIdx.x; c < end; c += NTHR) {
                const int k = c % uD2;
                const int t = c / uD2;
                const int j = t % uD1;
                const int i = t / uD1;
                const int x = u0 + i, y = u1 + j, z = u2 + k;
                float ax = 0.f, ay = 0.f, az = 0.f, aw = 0.f;
                for (int b = 0; b < NBLK; ++b) {
                    if (metaL[b][6] == 0 && metaL[b][3] > 0) {
                        const int dx = x - metaL[b][0];
                        const int dy = y - metaL[b][1];
                        const int dz = z - metaL[b][2];
                        if ((unsigned)dx < (unsigned)metaL[b][3] &&
                            (unsigned)dy < (unsigned)metaL[b][4] &&
                            (unsigned)dz < (unsigned)metaL[b][5]) {
                            const float4 tq = cell_load(
                                &priv[b * TCOUT + (dx * metaL[b][4] + dy) * metaL[b][5] + dz]);
                            ax += tq.x; ay += tq.y; az += tq.z; aw += tq.w;
                        }
                    }
                }
                const int gidx = (x * G + y) * G + z;
                cell_store(&redg[gidx], ax, ay, az, aw);
                if (outF) fstore(&outF[gidx], vs + aw);
            }
        }

        if (anyOvf) {
            // uniform extra barrier: owner baseline stores visible, then the
            // rare oversized block adds its particles directly (atomics).
            gridbar(barcnt, barflag, &lflag, ++gen);
            if (myOvf && act) {
                #pragma unroll
                for (int t = 0; t < 7; ++t) {
                    const int c = sub + 4 * t;
                    if (c >= 27) break;
                    const int oi = c / 9;
                    const int rem = c - 9 * oi;
                    const int oj = rem / 3;
                    const int ok = rem - 3 * oj;
                    const int nx = clampi(sb0 + oi);
                    const int ny = clampi(sb1 + oj);
                    const int nz = clampi(sb2 + ok);
                    const float dpx = ((float)oi - fx0) * DXc;
                    const float dpy = ((float)oj - fx1) * DXc;
                    const float dpz = ((float)ok - fx2) * DXc;
                    const float w = WA[oi] * WB[oj] * WC[ok];
                    const int gidx = (nx * G + ny) * G + nz;
                    float* gp = reinterpret_cast<float*>(&redg[gidx]);
                    unsafeAtomicAdd(gp + 0, w * (mvx + A00 * dpx + A01 * dpy + A02 * dpz));
                    unsafeAtomicAdd(gp + 1, w * (mvy + A10 * dpx + A11 * dpy + A12 * dpz));
                    unsafeAtomicAdd(gp + 2, w * (mvz + A20 * dpx + A21 * dpy + A22 * dpz));
                    unsafeAtomicAdd(gp + 3, w * P_MASS);
                    if (outF) unsafeAtomicAdd(&outF[gidx], w * P_MASS);
                }
            }
        }

        if (p < NSUB - 1) gridbar(barcnt, barflag, &lflag, ++gen);   // #2
        // last substep: kernel-end implicit release publishes redg/out stores
    }
}

extern "C" void kernel_launch(void* const* d_in, const int* in_sizes, int n_in,
                              void* d_out, int out_size, void* d_ws, size_t ws_size,
                              hipStream_t stream) {
    const float* v  = (const float*)d_in[0];
    const float* q  = (const float*)d_in[1];
    const float* qd = (const float*)d_in[2];
    float* out = (float*)d_out;
    float* ws  = (float*)d_ws;
    // barrier lines at the tail of the workspace (beyond priv/redg/meta usage)
    char* tail = (char*)d_ws + (ws_size & ~(size_t)255);
    unsigned* barcnt  = reinterpret_cast<unsigned*>(tail - 256);
    unsigned* barflag = reinterpret_cast<unsigned*>(tail - 512);
    void* args[] = { (void*)&v, (void*)&q, (void*)&qd, (void*)&out, (void*)&ws,
                     (void*)&barcnt, (void*)&barflag };
    hipLaunchCooperativeKernel(reinterpret_cast<void*>(mpm_sim),
                               dim3(NBLK), dim3(NTHR), args, 0, stream);
}

// Round 8
// 23635.054 us; speedup vs baseline: 1.8908x; 1.8908x over previous
//
#include <hip/hip_runtime.h>
#include <hip/hip_cooperative_groups.h>
#include <climits>

namespace cg = cooperative_groups;

static constexpr int G    = 100;
static constexpr int G3   = G * G * G;
static constexpr int NSUB   = 600;     // 20 frames x 30 substeps
static constexpr int SPF    = 30;      // substeps per frame
static constexpr int NSTEPS = 20;      // frames
static constexpr int NTHR   = 512;     // 8 waves/block
static constexpr int NBLK   = 108;     // 6x3x6 bricks of 5x5x5 particles
static constexpr int TCIN   = 2048;    // LDS IN-tile capacity (float4/cell = 32 KB)
static constexpr int TCOUT  = 2048;    // LDS OUT-tile capacity (4 floats/cell = 32 KB)

__device__ __forceinline__ int clampi(int v) {
    return v < 0 ? 0 : (v > G - 1 ? G - 1 : v);
}
__device__ __forceinline__ int maxi(int a, int b) { return a > b ? a : b; }
__device__ __forceinline__ int mini(int a, int b) { return a < b ? a : b; }

// MALL-coherent (agent-scope, relaxed) helpers. ALL grid traffic goes through
// these or agent-scope atomics, so the grid is never cached dirty in any L2 ->
// the grid barrier needs NO cache maintenance.
__device__ __forceinline__ float4 cell_load(const float4* p) {
    const unsigned long long* q = reinterpret_cast<const unsigned long long*>(p);
    unsigned long long a = __hip_atomic_load(&q[0], __ATOMIC_RELAXED, __HIP_MEMORY_SCOPE_AGENT);
    unsigned long long b = __hip_atomic_load(&q[1], __ATOMIC_RELAXED, __HIP_MEMORY_SCOPE_AGENT);
    float4 r;
    r.x = __uint_as_float((unsigned)(a & 0xffffffffu));
    r.y = __uint_as_float((unsigned)(a >> 32));
    r.z = __uint_as_float((unsigned)(b & 0xffffffffu));
    r.w = __uint_as_float((unsigned)(b >> 32));
    return r;
}
__device__ __forceinline__ void cell_zero(float4* p) {
    unsigned long long* q = reinterpret_cast<unsigned long long*>(p);
    __hip_atomic_store(&q[0], 0ull, __ATOMIC_RELAXED, __HIP_MEMORY_SCOPE_AGENT);
    __hip_atomic_store(&q[1], 0ull, __ATOMIC_RELAXED, __HIP_MEMORY_SCOPE_AGENT);
}
__device__ __forceinline__ int iload(const int* p) {
    return __hip_atomic_load(p, __ATOMIC_RELAXED, __HIP_MEMORY_SCOPE_AGENT);
}
__device__ __forceinline__ void istore(int* p, int v) {
    __hip_atomic_store(p, v, __ATOMIC_RELAXED, __HIP_MEMORY_SCOPE_AGENT);
}

// LDS-visibility-only block barrier (S1/S2/S3). Global stores are ordered once,
// at the grid barrier's full __syncthreads(). sched_barrier(0) per rule #18.
__device__ __forceinline__ void bar_lds() {
    __builtin_amdgcn_sched_barrier(0);
    asm volatile("s_waitcnt lgkmcnt(0)" ::: "memory");
    __builtin_amdgcn_s_barrier();
    __builtin_amdgcn_sched_barrier(0);
}

// Persistent cooperative kernel, triple-buffered float4 grid in ws:
//   g4[buf*G3 + idx] = (mom.x, mom.y, mom.z, mass)
// ROUND-8: REVERT to the r1 baseline (17.21ms, best measured) with ONE
// surgical change along the confirmed mechanism (r5: same-line MALL ops
// serialize at ~2.7ns/op/slice; r2: distinct-line stores are ~free):
// the p-2 zeroing (37K cells, 8-14x redundant writers on the same hot
// lines, ~5us/substep of serialized store service) is replaced by
// SINGLE-WRITER UNION ZEROING: each block publishes its 6-int true bbox
// into a 3-generation meta ring (overlaid on never-touched tail cells of
// grid buffer 2); at p>=2 every block reads the 108 metas of substep p-2
// (one LDS-staged pass folded into the existing S1 barrier), computes the
// union redundantly in registers, and zeroes a disjoint 1/108 slice of it
// (~52 cells/block, ~6.7x fewer stores, zero line sharing).
// Everything else (staging, G2P, physics, LDS scatter, flush atomics, out
// prefill, one hot split-line grid barrier per substep) is r1-identical.
__launch_bounds__(NTHR)
__global__ void mpm_sim(const float* __restrict__ vscal,
                        const float* __restrict__ q0,
                        const float* __restrict__ qd0,
                        float* __restrict__ out,
                        float* __restrict__ ws,
                        unsigned* __restrict__ barcnt,
                        unsigned* __restrict__ barflag)
{
    const float vs = vscal[0];
    float4* const g4 = reinterpret_cast<float4*>(ws);
    // 3-generation bbox-meta ring, overlaid on the last 1024 cells of grid
    // buffer 2 (grid idx >= G3-1024 -> x==99, y>=89: unreachable by the
    // centered particle block; zero-initialized with the grid, so p<2 reads
    // see dims==0). Layout: meta[p%3][NBLK][8] ints (bbox min/max, 2 pad).
    int* const metaG = reinterpret_cast<int*>(g4 + 3 * G3 - 1024);

    cg::grid_group gg = cg::this_grid();
    const int tid = blockIdx.x * NTHR + threadIdx.x;
    const int nth = NBLK * NTHR;

    __shared__ float4 tileIn[TCIN];        // normalized grid velocity per cell
    __shared__ float  tileOut[4 * TCOUT];  // scatter accum: [mx,my,mz,mass]
    __shared__ int    metaL[NBLK][8];      // p-2 bboxes (union zeroing)
    __shared__ int    sred[6];             // true-bbox reduction
    __shared__ unsigned lflag;             // LDS broadcast of barrier generation

    // ---- init: zero all 3 grid buffers (incl. meta overlay), vs-fill ALL
    // out slabs (r2-proven), reset barrier lines (ws poisoned 0xAA) ----
    {
        const float4 z = make_float4(0.f, 0.f, 0.f, 0.f);
        for (int i = tid; i < 3 * G3; i += nth) g4[i] = z;
        float4* o4 = reinterpret_cast<float4*>(out);
        const float4 vf = make_float4(vs, vs, vs, vs);
        const int on4 = NSTEPS * G3 / 4;
        for (int i = tid; i < on4; i += nth) o4[i] = vf;
        if (tid == 0) {
            __hip_atomic_store(barcnt,  0u, __ATOMIC_RELAXED, __HIP_MEMORY_SCOPE_AGENT);
            __hip_atomic_store(barflag, 0u, __ATOMIC_RELAXED, __HIP_MEMORY_SCOPE_AGENT);
        }
        if (threadIdx.x == 0) lflag = 0u;
    }

    // ---- particle state, replicated across the 4 lanes of a group ----
    const int slot = threadIdx.x >> 2;        // 0..127
    const int sub  = threadIdx.x & 3;         // lane within particle group
    const bool act = slot < 125;
    int pid = 0;
    if (act) {
        const int b  = blockIdx.x;            // (bx*3+by)*6+bz
        const int bx = b / 18;
        const int by = (b / 6) % 3;
        const int bz = b % 6;
        const int lx = slot / 25;
        const int rem = slot % 25;
        const int ly = rem / 5;
        const int lz = rem % 5;
        pid = ((bx * 5 + lx) * 15 + (by * 5 + ly)) * 30 + (bz * 5 + lz);
    }

    const float DT      = 5e-4f;
    const float INV_DX  = 100.0f;
    const float DXc     = 0.01f;
    const float MU      = (float)(1.0e5 / (2.0 * (1.0 + 0.3)));
    const float LAM     = (float)(1.0e5 * 0.3 / ((1.0 + 0.3) * (1.0 - 0.6)));
    const float P_MASS  = (float)(0.005 * 0.005 * 0.005 * 3000.0);
    const float KS      = (float)(-5.0e-4 * (0.005 * 0.005 * 0.005) * 4.0 * 100.0 * 100.0);
    const float DTG     = (float)(5.0e-4 * (-9.8));
    const float CSC     = 4.0f * INV_DX * INV_DX;   // 40000

    float px = 0.f, py = 0.f, pz = 0.f, vx = 0.f, vy = 0.f, vz = 0.f;
    float C00 = 0.f, C01 = 0.f, C02 = 0.f,
          C10 = 0.f, C11 = 0.f, C12 = 0.f,
          C20 = 0.f, C21 = 0.f, C22 = 0.f;
    float F00 = 1.f, F01 = 0.f, F02 = 0.f,
          F10 = 0.f, F11 = 1.f, F12 = 0.f,
          F20 = 0.f, F21 = 0.f, F22 = 1.f;
    if (act) {
        px = q0[3 * pid + 0]; py = q0[3 * pid + 1]; pz = q0[3 * pid + 2];
        vx = qd0[3 * pid + 0]; vy = qd0[3 * pid + 1]; vz = qd0[3 * pid + 2];
    }

    // per-wg TRUE bbox history (uniform across wg): p-1 scatter bbox
    int pmn0 = 0, pmn1 = 0, pmn2 = 0, pmx0 = -1, pmx1 = -1, pmx2 = -1; bool pvalid = false;

    gg.sync();   // publish init (release) before first phase

    unsigned gen = 0;

    for (int p = 0; p < NSUB; ++p) {
        const int bS = p % 3;
        const int bG = (p + 2) % 3;   // (p-1)%3 for p>0
        const int bZ = (p + 1) % 3;   // holds substep p-2 data
        float4*       __restrict__ gS4 = g4 + bS * G3;
        const float4* __restrict__ gG4 = g4 + bG * G3;
        float4*       __restrict__ gZ4 = g4 + bZ * G3;
        const int fc = p % SPF;
        float* const outF = (fc == SPF - 1) ? (out + (p / SPF) * G3) : nullptr;

        // grown scatter tile = prev true bbox +1 cell each side (fast path;
        // per-substep motion < 0.15 cells -> no bbox sync needed)
        const int tmn0 = pvalid ? maxi(pmn0 - 1, 0) : 0;
        const int tmn1 = pvalid ? maxi(pmn1 - 1, 0) : 0;
        const int tmn2 = pvalid ? maxi(pmn2 - 1, 0) : 0;
        const int tD0  = pvalid ? (mini(pmx0 + 1, G - 1) - tmn0 + 1) : 0;
        const int tD1  = pvalid ? (mini(pmx1 + 1, G - 1) - tmn1 + 1) : 0;
        const int tD2  = pvalid ? (mini(pmx2 + 1, G - 1) - tmn2 + 1) : 0;
        const int tvol = pvalid ? tD0 * tD1 * tD2 : 0;
        const bool fast = pvalid && (tvol <= TCOUT);

        // ---- [pre-S1] ----
        if (threadIdx.x == 0) {
            sred[0] = INT_MAX; sred[1] = INT_MAX; sred[2] = INT_MAX;
            sred[3] = INT_MIN; sred[4] = INT_MIN; sred[5] = INT_MIN;
        }
        // p-2 meta -> LDS (ring slot (p+1)%3 == (p-2)%3; zero-init -> dims 0
        // for p<2, so the union below is naturally empty)
        {
            const int* metaR = metaG + ((p + 1) % 3) * NBLK * 8;
            for (int i = threadIdx.x; i < NBLK * 8; i += NTHR)
                (&metaL[0][0])[i] = iload(&metaR[i]);
        }
        // stage gather region (own p-1 TRUE scatter bbox) -> tileIn, norm+BC
        const int iD1 = pvalid ? (pmx1 - pmn1 + 1) : 0;
        const int iD2 = pvalid ? (pmx2 - pmn2 + 1) : 0;
        const int inVol = pvalid ? (pmx0 - pmn0 + 1) * iD1 * iD2 : 0;
        const bool staged = pvalid && (inVol <= TCIN);
        if (staged) {
            for (int c = threadIdx.x; c < inVol; c += NTHR) {
                const int k = c % iD2;
                const int t = c / iD2;
                const int j = t % iD1;
                const int i = t / iD1;
                const int nx = pmn0 + i, ny = pmn1 + j, nz = pmn2 + k;
                const float4 gq = cell_load(&gG4[(nx * G + ny) * G + nz]);
                const float den = gq.w + vs;
                float gvx = gq.x / den;
                float gvy = gq.y / den;
                float gvz = gq.z / den;
                if (nx < 3       && gvx < 0.f) gvx = 0.f;
                if (nx >= G - 3  && gvx > 0.f) gvx = 0.f;
                if (ny < 3       && gvy < 0.f) gvy = 0.f;
                if (ny >= G - 3  && gvy > 0.f) gvy = 0.f;
                if (nz < 3       && gvz < 0.f) gvz = 0.f;
                if (nz >= G - 3  && gvz > 0.f) gvz = 0.f;
                tileIn[c] = make_float4(gvx, gvy, gvz, 0.f);
            }
        }
        // tileOut zero (grown tile in fast path, full capacity in fallback)
        {
            float4* t4 = reinterpret_cast<float4*>(tileOut);
            const float4 z = make_float4(0.f, 0.f, 0.f, 0.f);
            const int zn = fast ? tvol : TCOUT;
            for (int i = threadIdx.x; i < zn; i += NTHR) t4[i] = z;
        }
        bar_lds();   // S1: tileIn/tileOut/sred/metaL visible (LDS only)

        // ---- single-writer union zeroing of buffer p-2 (replaces per-block
        // redundant hot-line zeroing). Union computed redundantly per thread
        // from metaL (broadcast LDS reads); each block zeroes a disjoint
        // 1/NBLK flat slice. Fire-and-forget; drained at the grid barrier. ----
        if (p >= 2) {
            int u0 = INT_MAX, u1 = INT_MAX, u2 = INT_MAX;
            int v0 = INT_MIN, v1 = INT_MIN, v2 = INT_MIN;
            #pragma unroll 4
            for (int b = 0; b < NBLK; ++b) {
                if (metaL[b][3] >= metaL[b][0]) {   // valid bbox
                    u0 = mini(u0, metaL[b][0]); v0 = maxi(v0, metaL[b][3]);
                    u1 = mini(u1, metaL[b][1]); v1 = maxi(v1, metaL[b][4]);
                    u2 = mini(u2, metaL[b][2]); v2 = maxi(v2, metaL[b][5]);
                }
            }
            if (v0 >= u0) {
                const int uD0 = v0 - u0 + 1, uD1 = v1 - u1 + 1, uD2 = v2 - u2 + 1;
                const int vol = uD0 * uD1 * uD2;
                const int per = (vol + NBLK - 1) / NBLK;
                const int beg = (int)blockIdx.x * per;
                const int end = mini(beg + per, vol);
                for (int c = beg + (int)threadIdx.x; c < end; c += NTHR) {
                    const int k = c % uD2;
                    const int t = c / uD2;
                    const int j = t % uD1;
                    const int i = t / uD1;
                    cell_zero(&gZ4[((u0 + i) * G + (u1 + j)) * G + (u2 + k)]);
                }
            }
        }

        int sb0 = 0, sb1 = 0, sb2 = 0;
        float fx0 = 0.f, fx1 = 0.f, fx2 = 0.f;
        float A00 = 0.f, A01 = 0.f, A02 = 0.f,
              A10 = 0.f, A11 = 0.f, A12 = 0.f,
              A20 = 0.f, A21 = 0.f, A22 = 0.f;
        float mvx = 0.f, mvy = 0.f, mvz = 0.f;

        if (act) {
            // ======== G2P gather for substep p-1 (cells c%4==sub per lane) ========
            if (p > 0) {
                const float xs0 = px * INV_DX, xs1 = py * INV_DX, xs2 = pz * INV_DX;
                const float fb0 = floorf(xs0 - 0.5f), fb1 = floorf(xs1 - 0.5f), fb2 = floorf(xs2 - 0.5f);
                const int b0 = (int)fb0, b1 = (int)fb1, b2 = (int)fb2;
                const float gx0 = xs0 - fb0, gx1 = xs1 - fb1, gx2 = xs2 - fb2;
                float wa[3], wb[3], wc[3];
                wa[0] = 0.5f * (1.5f - gx0) * (1.5f - gx0);
                wa[1] = 0.75f - (gx0 - 1.0f) * (gx0 - 1.0f);
                wa[2] = 0.5f * (gx0 - 0.5f) * (gx0 - 0.5f);
                wb[0] = 0.5f * (1.5f - gx1) * (1.5f - gx1);
                wb[1] = 0.75f - (gx1 - 1.0f) * (gx1 - 1.0f);
                wb[2] = 0.5f * (gx1 - 0.5f) * (gx1 - 0.5f);
                wc[0] = 0.5f * (1.5f - gx2) * (1.5f - gx2);
                wc[1] = 0.75f - (gx2 - 1.0f) * (gx2 - 1.0f);
                wc[2] = 0.5f * (gx2 - 0.5f) * (gx2 - 0.5f);

                float nvx = 0.f, nvy = 0.f, nvz = 0.f;
                float nc00 = 0.f, nc01 = 0.f, nc02 = 0.f,
                      nc10 = 0.f, nc11 = 0.f, nc12 = 0.f,
                      nc20 = 0.f, nc21 = 0.f, nc22 = 0.f;
                #pragma unroll
                for (int t = 0; t < 7; ++t) {
                    const int c = sub + 4 * t;
                    if (c >= 27) break;
                    const int oi = c / 9;
                    const int rem = c - 9 * oi;
                    const int oj = rem / 3;
                    const int ok = rem - 3 * oj;
                    const int nx = clampi(b0 + oi);
                    const int ny = clampi(b1 + oj);
                    const int nz = clampi(b2 + ok);
                    const float dpx = ((float)oi - gx0) * DXc;
                    const float dpy = ((float)oj - gx1) * DXc;
                    const float dpz = ((float)ok - gx2) * DXc;
                    const float w = wa[oi] * wb[oj] * wc[ok];
                    float gvx, gvy, gvz;
                    if (staged) {
                        const float4 gv4 = tileIn[((nx - pmn0) * iD1 + (ny - pmn1)) * iD2 + (nz - pmn2)];
                        gvx = gv4.x; gvy = gv4.y; gvz = gv4.z;
                    } else {
                        const float4 gq = cell_load(&gG4[(nx * G + ny) * G + nz]);
                        const float den = gq.w + vs;
                        gvx = gq.x / den;
                        gvy = gq.y / den;
                        gvz = gq.z / den;
                        if (nx < 3       && gvx < 0.f) gvx = 0.f;
                        if (nx >= G - 3  && gvx > 0.f) gvx = 0.f;
                        if (ny < 3       && gvy < 0.f) gvy = 0.f;
                        if (ny >= G - 3  && gvy > 0.f) gvy = 0.f;
                        if (nz < 3       && gvz < 0.f) gvz = 0.f;
                        if (nz >= G - 3  && gvz > 0.f) gvz = 0.f;
                    }
                    nvx += w * gvx; nvy += w * gvy; nvz += w * gvz;
                    const float wgx = w * gvx, wgy = w * gvy, wgz = w * gvz;
                    nc00 += wgx * dpx; nc01 += wgx * dpy; nc02 += wgx * dpz;
                    nc10 += wgy * dpx; nc11 += wgy * dpy; nc12 += wgy * dpz;
                    nc20 += wgz * dpx; nc21 += wgz * dpy; nc22 += wgz * dpz;
                }
                // 4-lane butterfly: all lanes end with identical full sums
                #define BFLY(v) { v += __shfl_xor(v, 1); v += __shfl_xor(v, 2); }
                BFLY(nvx) BFLY(nvy) BFLY(nvz)
                BFLY(nc00) BFLY(nc01) BFLY(nc02)
                BFLY(nc10) BFLY(nc11) BFLY(nc12)
                BFLY(nc20) BFLY(nc21) BFLY(nc22)
                #undef BFLY
                vx = nvx; vy = nvy; vz = nvz;
                C00 = CSC * nc00; C01 = CSC * nc01; C02 = CSC * nc02;
                C10 = CSC * nc10; C11 = CSC * nc11; C12 = CSC * nc12;
                C20 = CSC * nc20; C21 = CSC * nc21; C22 = CSC * nc22;
                px += DT * vx; py += DT * vy; pz += DT * vz;
            }

            // ======== F update: F = (I + DT*C) @ F (replicated) ========
            {
                const float t00 = F00 + DT * (C00 * F00 + C01 * F10 + C02 * F20);
                const float t01 = F01 + DT * (C00 * F01 + C01 * F11 + C02 * F21);
                const float t02 = F02 + DT * (C00 * F02 + C01 * F12 + C02 * F22);
                const float t10 = F10 + DT * (C10 * F00 + C11 * F10 + C12 * F20);
                const float t11 = F11 + DT * (C10 * F01 + C11 * F11 + C12 * F21);
                const float t12 = F12 + DT * (C10 * F02 + C11 * F12 + C12 * F22);
                const float t20 = F20 + DT * (C20 * F00 + C21 * F10 + C22 * F20);
                const float t21 = F21 + DT * (C20 * F01 + C21 * F11 + C22 * F21);
                const float t22 = F22 + DT * (C20 * F02 + C21 * F12 + C22 * F22);
                F00 = t00; F01 = t01; F02 = t02;
                F10 = t10; F11 = t11; F12 = t12;
                F20 = t20; F21 = t21; F22 = t22;
            }

            // ======== neo-Hookean PK1 stress -> affine (replicated) ========
            const float c00 = F11 * F22 - F12 * F21;
            const float c01 = F12 * F20 - F10 * F22;
            const float c02 = F10 * F21 - F11 * F20;
            const float det = F00 * c00 + F01 * c01 + F02 * c02;
            const float c10 = F02 * F21 - F01 * F22;
            const float c11 = F00 * F22 - F02 * F20;
            const float c12 = F01 * F20 - F00 * F21;
            const float c20 = F01 * F12 - F02 * F11;
            const float c21 = F02 * F10 - F00 * F12;
            const float c22 = F00 * F11 - F01 * F10;
            const float idet = 1.0f / det;
            const float lj = LAM * logf(fmaxf(det, 1e-6f));
            const float fit00 = c00 * idet, fit01 = c01 * idet, fit02 = c02 * idet;
            const float fit10 = c10 * idet, fit11 = c11 * idet, fit12 = c12 * idet;
            const float fit20 = c20 * idet, fit21 = c21 * idet, fit22 = c22 * idet;
            const float P00 = MU * (F00 - fit00) + lj * fit00;
            const float P01 = MU * (F01 - fit01) + lj * fit01;
            const float P02 = MU * (F02 - fit02) + lj * fit02;
            const float P10 = MU * (F10 - fit10) + lj * fit10;
            const float P11 = MU * (F11 - fit11) + lj * fit11;
            const float P12 = MU * (F12 - fit12) + lj * fit12;
            const float P20 = MU * (F20 - fit20) + lj * fit20;
            const float P21 = MU * (F21 - fit21) + lj * fit21;
            const float P22 = MU * (F22 - fit22) + lj * fit22;
            A00 = KS * (P00 * F00 + P01 * F01 + P02 * F02) + P_MASS * C00;
            A01 = KS * (P00 * F10 + P01 * F11 + P02 * F12) + P_MASS * C01;
            A02 = KS * (P00 * F20 + P01 * F21 + P02 * F22) + P_MASS * C02;
            A10 = KS * (P10 * F00 + P11 * F01 + P12 * F02) + P_MASS * C10;
            A11 = KS * (P10 * F10 + P11 * F11 + P12 * F12) + P_MASS * C11;
            A12 = KS * (P10 * F20 + P11 * F21 + P12 * F22) + P_MASS * C12;
            A20 = KS * (P20 * F00 + P21 * F01 + P22 * F02) + P_MASS * C20;
            A21 = KS * (P20 * F10 + P21 * F11 + P22 * F12) + P_MASS * C21;
            A22 = KS * (P20 * F20 + P21 * F21 + P22 * F22) + P_MASS * C22;

            // scatter base (from updated x)
            const float xs0 = px * INV_DX, xs1 = py * INV_DX, xs2 = pz * INV_DX;
            const float fb0 = floorf(xs0 - 0.5f), fb1 = floorf(xs1 - 0.5f), fb2 = floorf(xs2 - 0.5f);
            sb0 = (int)fb0; sb1 = (int)fb1; sb2 = (int)fb2;
            fx0 = xs0 - fb0; fx1 = xs1 - fb1; fx2 = xs2 - fb2;
            mvx = P_MASS * vx;
            mvy = P_MASS * (vy + DTG);
            mvz = P_MASS * vz;

            if (sub == 0) {   // true-bbox reduction (read only after S3)
                atomicMin(&sred[0], clampi(sb0)); atomicMax(&sred[3], clampi(sb0 + 2));
                atomicMin(&sred[1], clampi(sb1)); atomicMax(&sred[4], clampi(sb1 + 2));
                atomicMin(&sred[2], clampi(sb2)); atomicMax(&sred[5], clampi(sb2 + 2));
            }
        }

        // weights for scatter (replicated per lane group)
        float wa0 = 0.f, wa1 = 0.f, wa2 = 0.f, wb0 = 0.f, wb1 = 0.f, wb2 = 0.f,
              wcc0 = 0.f, wcc1 = 0.f, wcc2 = 0.f;
        if (act) {
            wa0 = 0.5f * (1.5f - fx0) * (1.5f - fx0);
            wa1 = 0.75f - (fx0 - 1.0f) * (fx0 - 1.0f);
            wa2 = 0.5f * (fx0 - 0.5f) * (fx0 - 0.5f);
            wb0 = 0.5f * (1.5f - fx1) * (1.5f - fx1);
            wb1 = 0.75f - (fx1 - 1.0f) * (fx1 - 1.0f);
            wb2 = 0.5f * (fx1 - 0.5f) * (fx1 - 0.5f);
            wcc0 = 0.5f * (1.5f - fx2) * (1.5f - fx2);
            wcc1 = 0.75f - (fx2 - 1.0f) * (fx2 - 1.0f);
            wcc2 = 0.5f * (fx2 - 0.5f) * (fx2 - 0.5f);
        }
        const float WA[3] = { wa0, wa1, wa2 };
        const float WB[3] = { wb0, wb1, wb2 };
        const float WC[3] = { wcc0, wcc1, wcc2 };

        if (fast) {
            // ======== scatter into grown tile, no bbox sync needed ========
            if (act) {
                #pragma unroll
                for (int t = 0; t < 7; ++t) {
                    const int c = sub + 4 * t;
                    if (c >= 27) break;
                    const int oi = c / 9;
                    const int rem = c - 9 * oi;
                    const int oj = rem / 3;
                    const int ok = rem - 3 * oj;
                    const int li  = clampi(sb0 + oi) - tmn0;
                    const int lj2 = clampi(sb1 + oj) - tmn1;
                    const int lk  = clampi(sb2 + ok) - tmn2;
                    const float dpx = ((float)oi - fx0) * DXc;
                    const float dpy = ((float)oj - fx1) * DXc;
                    const float dpz = ((float)ok - fx2) * DXc;
                    const float w = WA[oi] * WB[oj] * WC[ok];
                    const int c4 = 4 * ((li * tD1 + lj2) * tD2 + lk);
                    atomicAdd(&tileOut[c4 + 0], w * (mvx + A00 * dpx + A01 * dpy + A02 * dpz));
                    atomicAdd(&tileOut[c4 + 1], w * (mvy + A10 * dpx + A11 * dpy + A12 * dpz));
                    atomicAdd(&tileOut[c4 + 2], w * (mvz + A20 * dpx + A21 * dpy + A22 * dpz));
                    atomicAdd(&tileOut[c4 + 3], w * P_MASS);
                }
            }
            bar_lds();   // S3 (LDS-visibility only)
            // flush grown tile -> grid (agent atomics), skip empty cells
            for (int c = threadIdx.x; c < tvol; c += NTHR) {
                const float m = tileOut[4 * c + 3];
                if (m != 0.f) {
                    const int k = c % tD2;
                    const int t = c / tD2;
                    const int j = t % tD1;
                    const int i = t / tD1;
                    const int gidx = ((tmn0 + i) * G + (tmn1 + j)) * G + (tmn2 + k);
                    float* gp = reinterpret_cast<float*>(gS4 + gidx);
                    unsafeAtomicAdd(gp + 0, tileOut[4 * c + 0]);
                    unsafeAtomicAdd(gp + 1, tileOut[4 * c + 1]);
                    unsafeAtomicAdd(gp + 2, tileOut[4 * c + 2]);
                    unsafeAtomicAdd(gp + 3, m);
                    if (outF) unsafeAtomicAdd(&outF[gidx], m);
                }
            }
        } else {
            // ======== fallback: bbox-sync path (p==0 or oversized tile) ========
            bar_lds();   // S2: bbox ready (LDS-visibility only)
            const int mn0 = sred[0], mn1 = sred[1], mn2 = sred[2];
            const int mx0 = sred[3], mx1 = sred[4], mx2 = sred[5];
            const bool anyAct = (mx0 >= mn0);
            const int D1 = mx1 - mn1 + 1, D2 = mx2 - mn2 + 1;
            const int vol = anyAct ? (mx0 - mn0 + 1) * D1 * D2 : 0;
            const bool useLDS = anyAct && (vol <= TCOUT);
            if (useLDS) {
                if (act) {
                    #pragma unroll
                    for (int t = 0; t < 7; ++t) {
                        const int c = sub + 4 * t;
                        if (c >= 27) break;
                        const int oi = c / 9;
                        const int rem = c - 9 * oi;
                        const int oj = rem / 3;
                        const int ok = rem - 3 * oj;
                        const int li  = clampi(sb0 + oi) - mn0;
                        const int lj2 = clampi(sb1 + oj) - mn1;
                        const int lk  = clampi(sb2 + ok) - mn2;
                        const float dpx = ((float)oi - fx0) * DXc;
                        const float dpy = ((float)oj - fx1) * DXc;
                        const float dpz = ((float)ok - fx2) * DXc;
                        const float w = WA[oi] * WB[oj] * WC[ok];
                        const int c4 = 4 * ((li * D1 + lj2) * D2 + lk);
                        atomicAdd(&tileOut[c4 + 0], w * (mvx + A00 * dpx + A01 * dpy + A02 * dpz));
                        atomicAdd(&tileOut[c4 + 1], w * (mvy + A10 * dpx + A11 * dpy + A12 * dpz));
                        atomicAdd(&tileOut[c4 + 2], w * (mvz + A20 * dpx + A21 * dpy + A22 * dpz));
                        atomicAdd(&tileOut[c4 + 3], w * P_MASS);
                    }
                }
                bar_lds();   // S3
                for (int c = threadIdx.x; c < vol; c += NTHR) {
                    const float m = tileOut[4 * c + 3];
                    if (m != 0.f) {
                        const int k = c % D2;
                        const int t = c / D2;
                        const int j = t % D1;
                        const int i = t / D1;
                        const int gidx = ((mn0 + i) * G + (mn1 + j)) * G + (mn2 + k);
                        float* gp = reinterpret_cast<float*>(gS4 + gidx);
                        unsafeAtomicAdd(gp + 0, tileOut[4 * c + 0]);
                        unsafeAtomicAdd(gp + 1, tileOut[4 * c + 1]);
                        unsafeAtomicAdd(gp + 2, tileOut[4 * c + 2]);
                        unsafeAtomicAdd(gp + 3, m);
                        if (outF) unsafeAtomicAdd(&outF[gidx], m);
                    }
                }
            } else {
                if (anyAct && act) {
                    #pragma unroll
                    for (int t = 0; t < 7; ++t) {
                        const int c = sub + 4 * t;
                        if (c >= 27) break;
                        const int oi = c / 9;
                        const int rem = c - 9 * oi;
                        const int oj = rem / 3;
                        const int ok = rem - 3 * oj;
                        const int nx = clampi(sb0 + oi);
                        const int ny = clampi(sb1 + oj);
                        const int nz = clampi(sb2 + ok);
                        const float dpx = ((float)oi - fx0) * DXc;
                        const float dpy = ((float)oj - fx1) * DXc;
                        const float dpz = ((float)ok - fx2) * DXc;
                        const float w = WA[oi] * WB[oj] * WC[ok];
                        const int gidx = (nx * G + ny) * G + nz;
                        float* gp = reinterpret_cast<float*>(gS4 + gidx);
                        unsafeAtomicAdd(gp + 0, w * (mvx + A00 * dpx + A01 * dpy + A02 * dpz));
                        unsafeAtomicAdd(gp + 1, w * (mvy + A10 * dpx + A11 * dpy + A12 * dpz));
                        unsafeAtomicAdd(gp + 2, w * (mvz + A20 * dpx + A21 * dpy + A22 * dpz));
                        unsafeAtomicAdd(gp + 3, w * P_MASS);
                        if (outF) unsafeAtomicAdd(&outF[gidx], w * P_MASS);
                    }
                }
                bar_lds();   // S3 (uniform)
            }
        }

        // publish this substep's TRUE bbox into the meta ring (slot p%3);
        // read back at p+2 for union zeroing. Flushed cells are always
        // within this bbox (scatter targets are clamped [sb..sb+2] which
        // the sred reduction covers). Published before the grid barrier.
        if (threadIdx.x == 0) {
            int* m = metaG + ((p % 3) * NBLK + (int)blockIdx.x) * 8;
            istore(&m[0], sred[0]); istore(&m[1], sred[1]); istore(&m[2], sred[2]);
            istore(&m[3], sred[3]); istore(&m[4], sred[4]); istore(&m[5], sred[5]);
        }

        // shift TRUE bbox history (sred result valid after S3)
        pmn0 = sred[0]; pmn1 = sred[1]; pmn2 = sred[2];
        pmx0 = sred[3]; pmx1 = sred[4]; pmx2 = sred[5]; pvalid = (pmx0 >= pmn0);

        if (p < NSUB - 1) {
            // ---- grid barrier: full __syncthreads (vmcnt drain publishes all
            // flush/zero/meta stores), thread 0 is the sole global poller,
            // LDS-flag broadcast to the other waves ----
            ++gen;
            __syncthreads();
            if (threadIdx.x == 0) {
                const unsigned old = __hip_atomic_fetch_add(barcnt, 1u, __ATOMIC_RELAXED, __HIP_MEMORY_SCOPE_AGENT);
                if (old == gen * (unsigned)NBLK - 1u) {
                    __hip_atomic_store(barflag, gen, __ATOMIC_RELEASE, __HIP_MEMORY_SCOPE_AGENT);
                }
                while (__hip_atomic_load(barflag, __ATOMIC_RELAXED, __HIP_MEMORY_SCOPE_AGENT) < gen) { }
                __hip_atomic_store(&lflag, gen, __ATOMIC_RELAXED, __HIP_MEMORY_SCOPE_WORKGROUP);
            }
            while (__hip_atomic_load(&lflag, __ATOMIC_RELAXED, __HIP_MEMORY_SCOPE_WORKGROUP) < gen) { }
            asm volatile("" ::: "memory");
        }
        // last phase: kernel-end implicit release publishes the final out adds
    }
}

extern "C" void kernel_launch(void* const* d_in, const int* in_sizes, int n_in,
                              void* d_out, int out_size, void* d_ws, size_t ws_size,
                              hipStream_t stream) {
    const float* v  = (const float*)d_in[0];
    const float* q  = (const float*)d_in[1];
    const float* qd = (const float*)d_in[2];
    float* out = (float*)d_out;
    float* ws  = (float*)d_ws;
    // barrier lines at the tail of the workspace, separate 256B lines so the
    // poll stream never contests ownership of the arrival line
    char* tail = (char*)d_ws + (ws_size & ~(size_t)255);
    unsigned* barcnt  = reinterpret_cast<unsigned*>(tail - 256);
    unsigned* barflag = reinterpret_cast<unsigned*>(tail - 512);
    void* args[] = { (void*)&v, (void*)&q, (void*)&qd, (void*)&out, (void*)&ws,
                     (void*)&barcnt, (void*)&barflag };
    hipLaunchCooperativeKernel(reinterpret_cast<void*>(mpm_sim),
                               dim3(NBLK), dim3(NTHR), args, 0, stream);
}

// Round 9
// 17171.532 us; speedup vs baseline: 2.6025x; 1.3764x over previous
//
#include <hip/hip_runtime.h>
#include <hip/hip_cooperative_groups.h>
#include <climits>

namespace cg = cooperative_groups;

static constexpr int G    = 100;
static constexpr int G3   = G * G * G;
static constexpr int NSUB   = 600;     // 20 frames x 30 substeps
static constexpr int SPF    = 30;      // substeps per frame
static constexpr int NSTEPS = 20;      // frames
static constexpr int NTHR   = 512;     // 8 waves/block
static constexpr int NBLK   = 108;     // 6x3x6 bricks of 5x5x5 particles
static constexpr int TCIN   = 2048;    // LDS IN-tile capacity (float4/cell = 32 KB)
static constexpr int TCOUT  = 2048;    // LDS OUT-tile capacity (4 floats/cell = 32 KB)

__device__ __forceinline__ int clampi(int v) {
    return v < 0 ? 0 : (v > G - 1 ? G - 1 : v);
}
__device__ __forceinline__ int maxi(int a, int b) { return a > b ? a : b; }
__device__ __forceinline__ int mini(int a, int b) { return a < b ? a : b; }

// MALL-coherent (agent-scope, relaxed) helpers. ALL grid traffic goes through
// these or agent-scope atomics, so the grid is never cached dirty in any L2 ->
// the grid barrier needs NO cache maintenance.
__device__ __forceinline__ float4 cell_load(const float4* p) {
    const unsigned long long* q = reinterpret_cast<const unsigned long long*>(p);
    unsigned long long a = __hip_atomic_load(&q[0], __ATOMIC_RELAXED, __HIP_MEMORY_SCOPE_AGENT);
    unsigned long long b = __hip_atomic_load(&q[1], __ATOMIC_RELAXED, __HIP_MEMORY_SCOPE_AGENT);
    float4 r;
    r.x = __uint_as_float((unsigned)(a & 0xffffffffu));
    r.y = __uint_as_float((unsigned)(a >> 32));
    r.z = __uint_as_float((unsigned)(b & 0xffffffffu));
    r.w = __uint_as_float((unsigned)(b >> 32));
    return r;
}
__device__ __forceinline__ void cell_zero(float4* p) {
    unsigned long long* q = reinterpret_cast<unsigned long long*>(p);
    __hip_atomic_store(&q[0], 0ull, __ATOMIC_RELAXED, __HIP_MEMORY_SCOPE_AGENT);
    __hip_atomic_store(&q[1], 0ull, __ATOMIC_RELAXED, __HIP_MEMORY_SCOPE_AGENT);
}

// LDS-visibility-only block barrier (S1/S2/S3). Global stores are ordered once,
// at the grid barrier's full __syncthreads(). sched_barrier(0) per rule #18.
__device__ __forceinline__ void bar_lds() {
    __builtin_amdgcn_sched_barrier(0);
    asm volatile("s_waitcnt lgkmcnt(0)" ::: "memory");
    __builtin_amdgcn_s_barrier();
    __builtin_amdgcn_sched_barrier(0);
}

// Persistent cooperative kernel, triple-buffered float4 grid in ws:
//   g4[buf*G3 + idx] = (mom.x, mom.y, mom.z, mass)
// ROUND-9: REVERT to the best-measured configuration (r1 baseline workers +
// r4-verified out-init hoist; 17.21-17.28ms family). Session record:
//  - sync mechanics (r1), SCLK heaters (r2), FCLK/MCLK heaters (r3): null.
//  - dependent agent-load latency = 257ns (r4 probe).
//  - concentrated far-atomic RMW service ~2.7ns/op -> flush ~8-12us/substep
//    (r5 probe) -- the dominant removable term.
//  - ALL structures that remove the flush atomics measured WORSE at this
//    problem size: consumer-sum (r6, +14ms), owner-pass 2-barrier (r7,
//    +27ms), single-writer union zero (r8, +6.4ms; also proved plain
//    hot-line stores are ~free -- only RMWs serialize).
// Conclusion: the 1-barrier atomic-flush structure is a measured local
// optimum; this build restores it exactly.
__launch_bounds__(NTHR)
__global__ void mpm_sim(const float* __restrict__ vscal,
                        const float* __restrict__ q0,
                        const float* __restrict__ qd0,
                        float* __restrict__ out,
                        float* __restrict__ ws,
                        unsigned* __restrict__ barcnt,
                        unsigned* __restrict__ barflag)
{
    const float vs = vscal[0];
    float4* const g4 = reinterpret_cast<float4*>(ws);

    cg::grid_group gg = cg::this_grid();
    const int tid = blockIdx.x * NTHR + threadIdx.x;
    const int nth = NBLK * NTHR;

    __shared__ float4 tileIn[TCIN];        // normalized grid velocity per cell
    __shared__ float  tileOut[4 * TCOUT];  // scatter accum: [mx,my,mz,mass]
    __shared__ int sred[6];                // true-bbox reduction
    __shared__ unsigned lflag;             // LDS broadcast of barrier generation

    // ---- init: zero all 3 grid buffers, vs-fill ALL out slabs (r2/r4-proven
    // neutral and correct), reset barrier lines (ws poisoned 0xAA) ----
    {
        const float4 z = make_float4(0.f, 0.f, 0.f, 0.f);
        for (int i = tid; i < 3 * G3; i += nth) g4[i] = z;
        float4* o4 = reinterpret_cast<float4*>(out);
        const float4 vf = make_float4(vs, vs, vs, vs);
        const int on4 = NSTEPS * G3 / 4;
        for (int i = tid; i < on4; i += nth) o4[i] = vf;
        if (tid == 0) {
            __hip_atomic_store(barcnt,  0u, __ATOMIC_RELAXED, __HIP_MEMORY_SCOPE_AGENT);
            __hip_atomic_store(barflag, 0u, __ATOMIC_RELAXED, __HIP_MEMORY_SCOPE_AGENT);
        }
        if (threadIdx.x == 0) lflag = 0u;
    }

    // ---- particle state, replicated across the 4 lanes of a group ----
    const int slot = threadIdx.x >> 2;        // 0..127
    const int sub  = threadIdx.x & 3;         // lane within particle group
    const bool act = slot < 125;
    int pid = 0;
    if (act) {
        const int b  = blockIdx.x;            // (bx*3+by)*6+bz
        const int bx = b / 18;
        const int by = (b / 6) % 3;
        const int bz = b % 6;
        const int lx = slot / 25;
        const int rem = slot % 25;
        const int ly = rem / 5;
        const int lz = rem % 5;
        pid = ((bx * 5 + lx) * 15 + (by * 5 + ly)) * 30 + (bz * 5 + lz);
    }

    const float DT      = 5e-4f;
    const float INV_DX  = 100.0f;
    const float DXc     = 0.01f;
    const float MU      = (float)(1.0e5 / (2.0 * (1.0 + 0.3)));
    const float LAM     = (float)(1.0e5 * 0.3 / ((1.0 + 0.3) * (1.0 - 0.6)));
    const float P_MASS  = (float)(0.005 * 0.005 * 0.005 * 3000.0);
    const float KS      = (float)(-5.0e-4 * (0.005 * 0.005 * 0.005) * 4.0 * 100.0 * 100.0);
    const float DTG     = (float)(5.0e-4 * (-9.8));
    const float CSC     = 4.0f * INV_DX * INV_DX;   // 40000

    float px = 0.f, py = 0.f, pz = 0.f, vx = 0.f, vy = 0.f, vz = 0.f;
    float C00 = 0.f, C01 = 0.f, C02 = 0.f,
          C10 = 0.f, C11 = 0.f, C12 = 0.f,
          C20 = 0.f, C21 = 0.f, C22 = 0.f;
    float F00 = 1.f, F01 = 0.f, F02 = 0.f,
          F10 = 0.f, F11 = 1.f, F12 = 0.f,
          F20 = 0.f, F21 = 0.f, F22 = 1.f;
    if (act) {
        px = q0[3 * pid + 0]; py = q0[3 * pid + 1]; pz = q0[3 * pid + 2];
        vx = qd0[3 * pid + 0]; vy = qd0[3 * pid + 1]; vz = qd0[3 * pid + 2];
    }

    // per-wg TRUE bbox history (uniform across wg): p-1 and p-2 scatter bboxes
    int pmn0 = 0, pmn1 = 0, pmn2 = 0, pmx0 = -1, pmx1 = -1, pmx2 = -1; bool pvalid = false;
    int zmn0 = 0, zmn1 = 0, zmn2 = 0, zmx0 = -1, zmx1 = -1, zmx2 = -1; bool zvalid = false;

    gg.sync();   // publish init (release) before first phase

    unsigned gen = 0;

    for (int p = 0; p < NSUB; ++p) {
        const int bS = p % 3;
        const int bG = (p + 2) % 3;   // (p-1)%3 for p>0
        const int bZ = (p + 1) % 3;   // holds substep p-2 data
        float4*       __restrict__ gS4 = g4 + bS * G3;
        const float4* __restrict__ gG4 = g4 + bG * G3;
        float4*       __restrict__ gZ4 = g4 + bZ * G3;
        const int fc = p % SPF;
        float* const outF = (fc == SPF - 1) ? (out + (p / SPF) * G3) : nullptr;

        // grown scatter tile = prev true bbox +1 cell each side (fast path;
        // per-substep motion < 0.15 cells -> no bbox sync needed)
        const int tmn0 = pvalid ? maxi(pmn0 - 1, 0) : 0;
        const int tmn1 = pvalid ? maxi(pmn1 - 1, 0) : 0;
        const int tmn2 = pvalid ? maxi(pmn2 - 1, 0) : 0;
        const int tD0  = pvalid ? (mini(pmx0 + 1, G - 1) - tmn0 + 1) : 0;
        const int tD1  = pvalid ? (mini(pmx1 + 1, G - 1) - tmn1 + 1) : 0;
        const int tD2  = pvalid ? (mini(pmx2 + 1, G - 1) - tmn2 + 1) : 0;
        const int tvol = pvalid ? tD0 * tD1 * tD2 : 0;
        const bool fast = pvalid && (tvol <= TCOUT);

        // ---- [pre-S1] staging FIRST: loads go in flight, everything below
        // (pure stores / LDS zeroing) overlaps their MALL latency ----
        const int iD1 = pvalid ? (pmx1 - pmn1 + 1) : 0;
        const int iD2 = pvalid ? (pmx2 - pmn2 + 1) : 0;
        const int inVol = pvalid ? (pmx0 - pmn0 + 1) * iD1 * iD2 : 0;
        const bool staged = pvalid && (inVol <= TCIN);
        if (staged) {
            for (int c = threadIdx.x; c < inVol; c += NTHR) {
                const int k = c % iD2;
                const int t = c / iD2;
                const int j = t % iD1;
                const int i = t / iD1;
                const int nx = pmn0 + i, ny = pmn1 + j, nz = pmn2 + k;
                const float4 gq = cell_load(&gG4[(nx * G + ny) * G + nz]);
                const float den = gq.w + vs;
                float gvx = gq.x / den;
                float gvy = gq.y / den;
                float gvz = gq.z / den;
                if (nx < 3       && gvx < 0.f) gvx = 0.f;
                if (nx >= G - 3  && gvx > 0.f) gvx = 0.f;
                if (ny < 3       && gvy < 0.f) gvy = 0.f;
                if (ny >= G - 3  && gvy > 0.f) gvy = 0.f;
                if (nz < 3       && gvz < 0.f) gvz = 0.f;
                if (nz >= G - 3  && gvz > 0.f) gvz = 0.f;
                tileIn[c] = make_float4(gvx, gvy, gvz, 0.f);
            }
        }
        // tileOut zero (grown tile in fast path, full capacity in fallback)
        {
            float4* t4 = reinterpret_cast<float4*>(tileOut);
            const float4 z = make_float4(0.f, 0.f, 0.f, 0.f);
            const int zn = fast ? tvol : TCOUT;
            for (int i = threadIdx.x; i < zn; i += NTHR) t4[i] = z;
        }
        // zero substep p-2's per-wg TRUE bbox (plain MALL stores; r8 showed
        // these hot-line stores are ~free -- only RMW atomics serialize)
        if (zvalid) {
            const int zD1 = zmx1 - zmn1 + 1, zD2 = zmx2 - zmn2 + 1;
            const int zvol = (zmx0 - zmn0 + 1) * zD1 * zD2;
            for (int c = threadIdx.x; c < zvol; c += NTHR) {
                const int k = c % zD2;
                const int t = c / zD2;
                const int j = t % zD1;
                const int i = t / zD1;
                cell_zero(&gZ4[((zmn0 + i) * G + (zmn1 + j)) * G + (zmn2 + k)]);
            }
        }
        if (threadIdx.x == 0) {
            sred[0] = INT_MAX; sred[1] = INT_MAX; sred[2] = INT_MAX;
            sred[3] = INT_MIN; sred[4] = INT_MIN; sred[5] = INT_MIN;
        }
        bar_lds();   // S1 (LDS-visibility only)

        int sb0 = 0, sb1 = 0, sb2 = 0;
        float fx0 = 0.f, fx1 = 0.f, fx2 = 0.f;
        float A00 = 0.f, A01 = 0.f, A02 = 0.f,
              A10 = 0.f, A11 = 0.f, A12 = 0.f,
              A20 = 0.f, A21 = 0.f, A22 = 0.f;
        float mvx = 0.f, mvy = 0.f, mvz = 0.f;

        if (act) {
            // ======== G2P gather for substep p-1 (cells c%4==sub per lane) ========
            if (p > 0) {
                const float xs0 = px * INV_DX, xs1 = py * INV_DX, xs2 = pz * INV_DX;
                const float fb0 = floorf(xs0 - 0.5f), fb1 = floorf(xs1 - 0.5f), fb2 = floorf(xs2 - 0.5f);
                const int b0 = (int)fb0, b1 = (int)fb1, b2 = (int)fb2;
                const float gx0 = xs0 - fb0, gx1 = xs1 - fb1, gx2 = xs2 - fb2;
                float wa[3], wb[3], wc[3];
                wa[0] = 0.5f * (1.5f - gx0) * (1.5f - gx0);
                wa[1] = 0.75f - (gx0 - 1.0f) * (gx0 - 1.0f);
                wa[2] = 0.5f * (gx0 - 0.5f) * (gx0 - 0.5f);
                wb[0] = 0.5f * (1.5f - gx1) * (1.5f - gx1);
                wb[1] = 0.75f - (gx1 - 1.0f) * (gx1 - 1.0f);
                wb[2] = 0.5f * (gx1 - 0.5f) * (gx1 - 0.5f);
                wc[0] = 0.5f * (1.5f - gx2) * (1.5f - gx2);
                wc[1] = 0.75f - (gx2 - 1.0f) * (gx2 - 1.0f);
                wc[2] = 0.5f * (gx2 - 0.5f) * (gx2 - 0.5f);

                float nvx = 0.f, nvy = 0.f, nvz = 0.f;
                float nc00 = 0.f, nc01 = 0.f, nc02 = 0.f,
                      nc10 = 0.f, nc11 = 0.f, nc12 = 0.f,
                      nc20 = 0.f, nc21 = 0.f, nc22 = 0.f;
                #pragma unroll
                for (int t = 0; t < 7; ++t) {
                    const int c = sub + 4 * t;
                    if (c >= 27) break;
                    const int oi = c / 9;
                    const int rem = c - 9 * oi;
                    const int oj = rem / 3;
                    const int ok = rem - 3 * oj;
                    const int nx = clampi(b0 + oi);
                    const int ny = clampi(b1 + oj);
                    const int nz = clampi(b2 + ok);
                    const float dpx = ((float)oi - gx0) * DXc;
                    const float dpy = ((float)oj - gx1) * DXc;
                    const float dpz = ((float)ok - gx2) * DXc;
                    const float w = wa[oi] * wb[oj] * wc[ok];
                    float gvx, gvy, gvz;
                    if (staged) {
                        const float4 gv4 = tileIn[((nx - pmn0) * iD1 + (ny - pmn1)) * iD2 + (nz - pmn2)];
                        gvx = gv4.x; gvy = gv4.y; gvz = gv4.z;
                    } else {
                        const float4 gq = cell_load(&gG4[(nx * G + ny) * G + nz]);
                        const float den = gq.w + vs;
                        gvx = gq.x / den;
                        gvy = gq.y / den;
                        gvz = gq.z / den;
                        if (nx < 3       && gvx < 0.f) gvx = 0.f;
                        if (nx >= G - 3  && gvx > 0.f) gvx = 0.f;
                        if (ny < 3       && gvy < 0.f) gvy = 0.f;
                        if (ny >= G - 3  && gvy > 0.f) gvy = 0.f;
                        if (nz < 3       && gvz < 0.f) gvz = 0.f;
                        if (nz >= G - 3  && gvz > 0.f) gvz = 0.f;
                    }
                    nvx += w * gvx; nvy += w * gvy; nvz += w * gvz;
                    const float wgx = w * gvx, wgy = w * gvy, wgz = w * gvz;
                    nc00 += wgx * dpx; nc01 += wgx * dpy; nc02 += wgx * dpz;
                    nc10 += wgy * dpx; nc11 += wgy * dpy; nc12 += wgy * dpz;
                    nc20 += wgz * dpx; nc21 += wgz * dpy; nc22 += wgz * dpz;
                }
                // 4-lane butterfly: all lanes end with identical full sums
                #define BFLY(v) { v += __shfl_xor(v, 1); v += __shfl_xor(v, 2); }
                BFLY(nvx) BFLY(nvy) BFLY(nvz)
                BFLY(nc00) BFLY(nc01) BFLY(nc02)
                BFLY(nc10) BFLY(nc11) BFLY(nc12)
                BFLY(nc20) BFLY(nc21) BFLY(nc22)
                #undef BFLY
                vx = nvx; vy = nvy; vz = nvz;
                C00 = CSC * nc00; C01 = CSC * nc01; C02 = CSC * nc02;
                C10 = CSC * nc10; C11 = CSC * nc11; C12 = CSC * nc12;
                C20 = CSC * nc20; C21 = CSC * nc21; C22 = CSC * nc22;
                px += DT * vx; py += DT * vy; pz += DT * vz;
            }

            // ======== F update: F = (I + DT*C) @ F (replicated) ========
            {
                const float t00 = F00 + DT * (C00 * F00 + C01 * F10 + C02 * F20);
                const float t01 = F01 + DT * (C00 * F01 + C01 * F11 + C02 * F21);
                const float t02 = F02 + DT * (C00 * F02 + C01 * F12 + C02 * F22);
                const float t10 = F10 + DT * (C10 * F00 + C11 * F10 + C12 * F20);
                const float t11 = F11 + DT * (C10 * F01 + C11 * F11 + C12 * F21);
                const float t12 = F12 + DT * (C10 * F02 + C11 * F12 + C12 * F22);
                const float t20 = F20 + DT * (C20 * F00 + C21 * F10 + C22 * F20);
                const float t21 = F21 + DT * (C20 * F01 + C21 * F11 + C22 * F21);
                const float t22 = F22 + DT * (C20 * F02 + C21 * F12 + C22 * F22);
                F00 = t00; F01 = t01; F02 = t02;
                F10 = t10; F11 = t11; F12 = t12;
                F20 = t20; F21 = t21; F22 = t22;
            }

            // ======== neo-Hookean PK1 stress -> affine (replicated) ========
            const float c00 = F11 * F22 - F12 * F21;
            const float c01 = F12 * F20 - F10 * F22;
            const float c02 = F10 * F21 - F11 * F20;
            const float det = F00 * c00 + F01 * c01 + F02 * c02;
            const float c10 = F02 * F21 - F01 * F22;
            const float c11 = F00 * F22 - F02 * F20;
            const float c12 = F01 * F20 - F00 * F21;
            const float c20 = F01 * F12 - F02 * F11;
            const float c21 = F02 * F10 - F00 * F12;
            const float c22 = F00 * F11 - F01 * F10;
            const float idet = 1.0f / det;
            const float lj = LAM * logf(fmaxf(det, 1e-6f));
            const float fit00 = c00 * idet, fit01 = c01 * idet, fit02 = c02 * idet;
            const float fit10 = c10 * idet, fit11 = c11 * idet, fit12 = c12 * idet;
            const float fit20 = c20 * idet, fit21 = c21 * idet, fit22 = c22 * idet;
            const float P00 = MU * (F00 - fit00) + lj * fit00;
            const float P01 = MU * (F01 - fit01) + lj * fit01;
            const float P02 = MU * (F02 - fit02) + lj * fit02;
            const float P10 = MU * (F10 - fit10) + lj * fit10;
            const float P11 = MU * (F11 - fit11) + lj * fit11;
            const float P12 = MU * (F12 - fit12) + lj * fit12;
            const float P20 = MU * (F20 - fit20) + lj * fit20;
            const float P21 = MU * (F21 - fit21) + lj * fit21;
            const float P22 = MU * (F22 - fit22) + lj * fit22;
            A00 = KS * (P00 * F00 + P01 * F01 + P02 * F02) + P_MASS * C00;
            A01 = KS * (P00 * F10 + P01 * F11 + P02 * F12) + P_MASS * C01;
            A02 = KS * (P00 * F20 + P01 * F21 + P02 * F22) + P_MASS * C02;
            A10 = KS * (P10 * F00 + P11 * F01 + P12 * F02) + P_MASS * C10;
            A11 = KS * (P10 * F10 + P11 * F11 + P12 * F12) + P_MASS * C11;
            A12 = KS * (P10 * F20 + P11 * F21 + P12 * F22) + P_MASS * C12;
            A20 = KS * (P20 * F00 + P21 * F01 + P22 * F02) + P_MASS * C20;
            A21 = KS * (P20 * F10 + P21 * F11 + P22 * F12) + P_MASS * C21;
            A22 = KS * (P20 * F20 + P21 * F21 + P22 * F22) + P_MASS * C22;

            // scatter base (from updated x)
            const float xs0 = px * INV_DX, xs1 = py * INV_DX, xs2 = pz * INV_DX;
            const float fb0 = floorf(xs0 - 0.5f), fb1 = floorf(xs1 - 0.5f), fb2 = floorf(xs2 - 0.5f);
            sb0 = (int)fb0; sb1 = (int)fb1; sb2 = (int)fb2;
            fx0 = xs0 - fb0; fx1 = xs1 - fb1; fx2 = xs2 - fb2;
            mvx = P_MASS * vx;
            mvy = P_MASS * (vy + DTG);
            mvz = P_MASS * vz;

            if (sub == 0) {   // true-bbox reduction (read only after S3)
                atomicMin(&sred[0], clampi(sb0)); atomicMax(&sred[3], clampi(sb0 + 2));
                atomicMin(&sred[1], clampi(sb1)); atomicMax(&sred[4], clampi(sb1 + 2));
                atomicMin(&sred[2], clampi(sb2)); atomicMax(&sred[5], clampi(sb2 + 2));
            }
        }

        // weights for scatter (replicated per lane group)
        float wa0 = 0.f, wa1 = 0.f, wa2 = 0.f, wb0 = 0.f, wb1 = 0.f, wb2 = 0.f,
              wcc0 = 0.f, wcc1 = 0.f, wcc2 = 0.f;
        if (act) {
            wa0 = 0.5f * (1.5f - fx0) * (1.5f - fx0);
            wa1 = 0.75f - (fx0 - 1.0f) * (fx0 - 1.0f);
            wa2 = 0.5f * (fx0 - 0.5f) * (fx0 - 0.5f);
            wb0 = 0.5f * (1.5f - fx1) * (1.5f - fx1);
            wb1 = 0.75f - (fx1 - 1.0f) * (fx1 - 1.0f);
            wb2 = 0.5f * (fx1 - 0.5f) * (fx1 - 0.5f);
            wcc0 = 0.5f * (1.5f - fx2) * (1.5f - fx2);
            wcc1 = 0.75f - (fx2 - 1.0f) * (fx2 - 1.0f);
            wcc2 = 0.5f * (fx2 - 0.5f) * (fx2 - 0.5f);
        }
        const float WA[3] = { wa0, wa1, wa2 };
        const float WB[3] = { wb0, wb1, wb2 };
        const float WC[3] = { wcc0, wcc1, wcc2 };

        if (fast) {
            // ======== scatter into grown tile, no bbox sync needed ========
            if (act) {
                #pragma unroll
                for (int t = 0; t < 7; ++t) {
                    const int c = sub + 4 * t;
                    if (c >= 27) break;
                    const int oi = c / 9;
                    const int rem = c - 9 * oi;
                    const int oj = rem / 3;
                    const int ok = rem - 3 * oj;
                    const int li  = clampi(sb0 + oi) - tmn0;
                    const int lj2 = clampi(sb1 + oj) - tmn1;
                    const int lk  = clampi(sb2 + ok) - tmn2;
                    const float dpx = ((float)oi - fx0) * DXc;
                    const float dpy = ((float)oj - fx1) * DXc;
                    const float dpz = ((float)ok - fx2) * DXc;
                    const float w = WA[oi] * WB[oj] * WC[ok];
                    const int c4 = 4 * ((li * tD1 + lj2) * tD2 + lk);
                    atomicAdd(&tileOut[c4 + 0], w * (mvx + A00 * dpx + A01 * dpy + A02 * dpz));
                    atomicAdd(&tileOut[c4 + 1], w * (mvy + A10 * dpx + A11 * dpy + A12 * dpz));
                    atomicAdd(&tileOut[c4 + 2], w * (mvz + A20 * dpx + A21 * dpy + A22 * dpz));
                    atomicAdd(&tileOut[c4 + 3], w * P_MASS);
                }
            }
            bar_lds();   // S3 (LDS-visibility only)
            // flush grown tile -> grid (agent atomics), skip empty cells
            for (int c = threadIdx.x; c < tvol; c += NTHR) {
                const float m = tileOut[4 * c + 3];
                if (m != 0.f) {
                    const int k = c % tD2;
                    const int t = c / tD2;
                    const int j = t % tD1;
                    const int i = t / tD1;
                    const int gidx = ((tmn0 + i) * G + (tmn1 + j)) * G + (tmn2 + k);
                    float* gp = reinterpret_cast<float*>(gS4 + gidx);
                    unsafeAtomicAdd(gp + 0, tileOut[4 * c + 0]);
                    unsafeAtomicAdd(gp + 1, tileOut[4 * c + 1]);
                    unsafeAtomicAdd(gp + 2, tileOut[4 * c + 2]);
                    unsafeAtomicAdd(gp + 3, m);
                    if (outF) unsafeAtomicAdd(&outF[gidx], m);
                }
            }
        } else {
            // ======== fallback: bbox-sync path (p==0 or oversized tile) ========
            bar_lds();   // S2: bbox ready (LDS-visibility only)
            const int mn0 = sred[0], mn1 = sred[1], mn2 = sred[2];
            const int mx0 = sred[3], mx1 = sred[4], mx2 = sred[5];
            const bool anyAct = (mx0 >= mn0);
            const int D1 = mx1 - mn1 + 1, D2 = mx2 - mn2 + 1;
            const int vol = anyAct ? (mx0 - mn0 + 1) * D1 * D2 : 0;
            const bool useLDS = anyAct && (vol <= TCOUT);
            if (useLDS) {
                if (act) {
                    #pragma unroll
                    for (int t = 0; t < 7; ++t) {
                        const int c = sub + 4 * t;
                        if (c >= 27) break;
                        const int oi = c / 9;
                        const int rem = c - 9 * oi;
                        const int oj = rem / 3;
                        const int ok = rem - 3 * oj;
                        const int li  = clampi(sb0 + oi) - mn0;
                        const int lj2 = clampi(sb1 + oj) - mn1;
                        const int lk  = clampi(sb2 + ok) - mn2;
                        const float dpx = ((float)oi - fx0) * DXc;
                        const float dpy = ((float)oj - fx1) * DXc;
                        const float dpz = ((float)ok - fx2) * DXc;
                        const float w = WA[oi] * WB[oj] * WC[ok];
                        const int c4 = 4 * ((li * D1 + lj2) * D2 + lk);
                        atomicAdd(&tileOut[c4 + 0], w * (mvx + A00 * dpx + A01 * dpy + A02 * dpz));
                        atomicAdd(&tileOut[c4 + 1], w * (mvy + A10 * dpx + A11 * dpy + A12 * dpz));
                        atomicAdd(&tileOut[c4 + 2], w * (mvz + A20 * dpx + A21 * dpy + A22 * dpz));
                        atomicAdd(&tileOut[c4 + 3], w * P_MASS);
                    }
                }
                bar_lds();   // S3
                for (int c = threadIdx.x; c < vol; c += NTHR) {
                    const float m = tileOut[4 * c + 3];
                    if (m != 0.f) {
                        const int k = c % D2;
                        const int t = c / D2;
                        const int j = t % D1;
                        const int i = t / D1;
                        const int gidx = ((mn0 + i) * G + (mn1 + j)) * G + (mn2 + k);
                        float* gp = reinterpret_cast<float*>(gS4 + gidx);
                        unsafeAtomicAdd(gp + 0, tileOut[4 * c + 0]);
                        unsafeAtomicAdd(gp + 1, tileOut[4 * c + 1]);
                        unsafeAtomicAdd(gp + 2, tileOut[4 * c + 2]);
                        unsafeAtomicAdd(gp + 3, m);
                        if (outF) unsafeAtomicAdd(&outF[gidx], m);
                    }
                }
            } else {
                if (anyAct && act) {
                    #pragma unroll
                    for (int t = 0; t < 7; ++t) {
                        const int c = sub + 4 * t;
                        if (c >= 27) break;
                        const int oi = c / 9;
                        const int rem = c - 9 * oi;
                        const int oj = rem / 3;
                        const int ok = rem - 3 * oj;
                        const int nx = clampi(sb0 + oi);
                        const int ny = clampi(sb1 + oj);
                        const int nz = clampi(sb2 + ok);
                        const float dpx = ((float)oi - fx0) * DXc;
                        const float dpy = ((float)oj - fx1) * DXc;
                        const float dpz = ((float)ok - fx2) * DXc;
                        const float w = WA[oi] * WB[oj] * WC[ok];
                        const int gidx = (nx * G + ny) * G + nz;
                        float* gp = reinterpret_cast<float*>(gS4 + gidx);
                        unsafeAtomicAdd(gp + 0, w * (mvx + A00 * dpx + A01 * dpy + A02 * dpz));
                        unsafeAtomicAdd(gp + 1, w * (mvy + A10 * dpx + A11 * dpy + A12 * dpz));
                        unsafeAtomicAdd(gp + 2, w * (mvz + A20 * dpx + A21 * dpy + A22 * dpz));
                        unsafeAtomicAdd(gp + 3, w * P_MASS);
                        if (outF) unsafeAtomicAdd(&outF[gidx], w * P_MASS);
                    }
                }
                bar_lds();   // S3 (uniform)
            }
        }

        // shift TRUE bbox history (sred result valid after S3)
        zmn0 = pmn0; zmn1 = pmn1; zmn2 = pmn2;
        zmx0 = pmx0; zmx1 = pmx1; zmx2 = pmx2; zvalid = pvalid;
        pmn0 = sred[0]; pmn1 = sred[1]; pmn2 = sred[2];
        pmx0 = sred[3]; pmx1 = sred[4]; pmx2 = sred[5]; pvalid = (pmx0 >= pmn0);

        if (p < NSUB - 1) {
            // ---- grid barrier: full __syncthreads (vmcnt drain publishes all
            // flush/zero stores), thread 0 is the sole global poller, LDS-flag
            // broadcast to the other waves ----
            ++gen;
            __syncthreads();
            if (threadIdx.x == 0) {
                const unsigned old = __hip_atomic_fetch_add(barcnt, 1u, __ATOMIC_RELAXED, __HIP_MEMORY_SCOPE_AGENT);
                if (old == gen * (unsigned)NBLK - 1u) {
                    __hip_atomic_store(barflag, gen, __ATOMIC_RELEASE, __HIP_MEMORY_SCOPE_AGENT);
                }
                while (__hip_atomic_load(barflag, __ATOMIC_RELAXED, __HIP_MEMORY_SCOPE_AGENT) < gen) { }
                __hip_atomic_store(&lflag, gen, __ATOMIC_RELAXED, __HIP_MEMORY_SCOPE_WORKGROUP);
            }
            while (__hip_atomic_load(&lflag, __ATOMIC_RELAXED, __HIP_MEMORY_SCOPE_WORKGROUP) < gen) { }
            asm volatile("" ::: "memory");
        }
        // last phase: kernel-end implicit release publishes the final out adds
    }
}

extern "C" void kernel_launch(void* const* d_in, const int* in_sizes, int n_in,
                              void* d_out, int out_size, void* d_ws, size_t ws_size,
                              hipStream_t stream) {
    const float* v  = (const float*)d_in[0];
    const float* q  = (const float*)d_in[1];
    const float* qd = (const float*)d_in[2];
    float* out = (float*)d_out;
    float* ws  = (float*)d_ws;
    // barrier lines at the tail of the workspace, separate 256B lines so the
    // poll stream never contests ownership of the arrival line
    char* tail = (char*)d_ws + (ws_size & ~(size_t)255);
    unsigned* barcnt  = reinterpret_cast<unsigned*>(tail - 256);
    unsigned* barflag = reinterpret_cast<unsigned*>(tail - 512);
    void* args[] = { (void*)&v, (void*)&q, (void*)&qd, (void*)&out, (void*)&ws,
                     (void*)&barcnt, (void*)&barflag };
    hipLaunchCooperativeKernel(reinterpret_cast<void*>(mpm_sim),
                               dim3(NBLK), dim3(NTHR), args, 0, stream);
}

// Round 10
// 15599.498 us; speedup vs baseline: 2.8647x; 1.1008x over previous
//
#include <hip/hip_runtime.h>
#include <hip/hip_cooperative_groups.h>
#include <climits>

namespace cg = cooperative_groups;

static constexpr int G    = 100;
static constexpr int G3   = G * G * G;
static constexpr int NSUB   = 600;     // 20 frames x 30 substeps
static constexpr int SPF    = 30;      // substeps per frame
static constexpr int NSTEPS = 20;      // frames
static constexpr int NTHR   = 512;     // 8 waves/block
static constexpr int NBLK   = 108;     // 6x3x6 bricks of 5x5x5 particles
static constexpr int TCIN   = 2048;    // LDS IN-tile capacity (float4/cell = 32 KB)
static constexpr int TCOUT  = 2048;    // LDS OUT-tile capacity (4 floats/cell = 32 KB)

__device__ __forceinline__ int clampi(int v) {
    return v < 0 ? 0 : (v > G - 1 ? G - 1 : v);
}
__device__ __forceinline__ int maxi(int a, int b) { return a > b ? a : b; }
__device__ __forceinline__ int mini(int a, int b) { return a < b ? a : b; }

// MALL-coherent (agent-scope, relaxed) helpers. ALL grid traffic goes through
// these or agent-scope atomics, so the grid is never cached dirty in any L2 ->
// the grid barrier needs NO cache maintenance.
__device__ __forceinline__ float fload_ag(const float* p) {
    return __hip_atomic_load(p, __ATOMIC_RELAXED, __HIP_MEMORY_SCOPE_AGENT);
}
__device__ __forceinline__ void fstore_ag(float* p, float v) {
    __hip_atomic_store(p, v, __ATOMIC_RELAXED, __HIP_MEMORY_SCOPE_AGENT);
}

// LDS-visibility-only block barrier (S1/S2/S3). Global stores are ordered once,
// at the grid barrier's full __syncthreads(). sched_barrier(0) per rule #18.
__device__ __forceinline__ void bar_lds() {
    __builtin_amdgcn_sched_barrier(0);
    asm volatile("s_waitcnt lgkmcnt(0)" ::: "memory");
    __builtin_amdgcn_s_barrier();
    __builtin_amdgcn_sched_barrier(0);
}

// Persistent cooperative kernel, triple-buffered SoA grid in ws:
//   gbuf[buf] = { momx[G3], momy[G3], momz[G3], mass[G3] }  (planes 4MB apart)
// ROUND-10 (last open uarch question): r5's probe (85ps/op chip-wide on the
// concentrated region) cannot distinguish chip-wide RMW throughput from
// PER-LINE RMW serialization. The AoS float4 flush is worst-case for the
// latter: each cell's 4 atomics hit the SAME 16B of the SAME line (4-deep
// same-line chains; ~150-200 RMWs per hot line across co-writers). This
// build switches the grid to SoA so each cell's 4 RMWs land on 4 DISTINCT
// lines in distinct slices and per-line op count drops 4x. Same structure,
// same op counts, same single barrier -- only the layout changes.
// If per-line serialization dominates: dur 17.2 -> ~13-15ms. If chip-wide
// throughput-bound: null -> measured structural floor established.
__launch_bounds__(NTHR)
__global__ void mpm_sim(const float* __restrict__ vscal,
                        const float* __restrict__ q0,
                        const float* __restrict__ qd0,
                        float* __restrict__ out,
                        float* __restrict__ ws,
                        unsigned* __restrict__ barcnt,
                        unsigned* __restrict__ barflag)
{
    const float vs = vscal[0];

    cg::grid_group gg = cg::this_grid();
    const int tid = blockIdx.x * NTHR + threadIdx.x;
    const int nth = NBLK * NTHR;

    __shared__ float4 tileIn[TCIN];        // normalized grid velocity per cell
    __shared__ float  tileOut[4 * TCOUT];  // scatter accum: [mx,my,mz,mass]
    __shared__ int sred[6];                // true-bbox reduction
    __shared__ unsigned lflag;             // LDS broadcast of barrier generation

    // ---- init: zero all 3 grid buffers (12*G3 floats), vs-fill ALL out
    // slabs (r2/r4-proven), reset barrier lines (ws poisoned 0xAA) ----
    {
        float4* w4 = reinterpret_cast<float4*>(ws);
        const float4 z = make_float4(0.f, 0.f, 0.f, 0.f);
        for (int i = tid; i < 3 * G3; i += nth) w4[i] = z;   // 12*G3 floats
        float4* o4 = reinterpret_cast<float4*>(out);
        const float4 vf = make_float4(vs, vs, vs, vs);
        const int on4 = NSTEPS * G3 / 4;
        for (int i = tid; i < on4; i += nth) o4[i] = vf;
        if (tid == 0) {
            __hip_atomic_store(barcnt,  0u, __ATOMIC_RELAXED, __HIP_MEMORY_SCOPE_AGENT);
            __hip_atomic_store(barflag, 0u, __ATOMIC_RELAXED, __HIP_MEMORY_SCOPE_AGENT);
        }
        if (threadIdx.x == 0) lflag = 0u;
    }

    // ---- particle state, replicated across the 4 lanes of a group ----
    const int slot = threadIdx.x >> 2;        // 0..127
    const int sub  = threadIdx.x & 3;         // lane within particle group
    const bool act = slot < 125;
    int pid = 0;
    if (act) {
        const int b  = blockIdx.x;            // (bx*3+by)*6+bz
        const int bx = b / 18;
        const int by = (b / 6) % 3;
        const int bz = b % 6;
        const int lx = slot / 25;
        const int rem = slot % 25;
        const int ly = rem / 5;
        const int lz = rem % 5;
        pid = ((bx * 5 + lx) * 15 + (by * 5 + ly)) * 30 + (bz * 5 + lz);
    }

    const float DT      = 5e-4f;
    const float INV_DX  = 100.0f;
    const float DXc     = 0.01f;
    const float MU      = (float)(1.0e5 / (2.0 * (1.0 + 0.3)));
    const float LAM     = (float)(1.0e5 * 0.3 / ((1.0 + 0.3) * (1.0 - 0.6)));
    const float P_MASS  = (float)(0.005 * 0.005 * 0.005 * 3000.0);
    const float KS      = (float)(-5.0e-4 * (0.005 * 0.005 * 0.005) * 4.0 * 100.0 * 100.0);
    const float DTG     = (float)(5.0e-4 * (-9.8));
    const float CSC     = 4.0f * INV_DX * INV_DX;   // 40000

    float px = 0.f, py = 0.f, pz = 0.f, vx = 0.f, vy = 0.f, vz = 0.f;
    float C00 = 0.f, C01 = 0.f, C02 = 0.f,
          C10 = 0.f, C11 = 0.f, C12 = 0.f,
          C20 = 0.f, C21 = 0.f, C22 = 0.f;
    float F00 = 1.f, F01 = 0.f, F02 = 0.f,
          F10 = 0.f, F11 = 1.f, F12 = 0.f,
          F20 = 0.f, F21 = 0.f, F22 = 1.f;
    if (act) {
        px = q0[3 * pid + 0]; py = q0[3 * pid + 1]; pz = q0[3 * pid + 2];
        vx = qd0[3 * pid + 0]; vy = qd0[3 * pid + 1]; vz = qd0[3 * pid + 2];
    }

    // per-wg TRUE bbox history (uniform across wg): p-1 and p-2 scatter bboxes
    int pmn0 = 0, pmn1 = 0, pmn2 = 0, pmx0 = -1, pmx1 = -1, pmx2 = -1; bool pvalid = false;
    int zmn0 = 0, zmn1 = 0, zmn2 = 0, zmx0 = -1, zmx1 = -1, zmx2 = -1; bool zvalid = false;

    gg.sync();   // publish init (release) before first phase

    unsigned gen = 0;

    for (int p = 0; p < NSUB; ++p) {
        const int bS = p % 3;
        const int bG = (p + 2) % 3;   // (p-1)%3 for p>0
        const int bZ = (p + 1) % 3;   // holds substep p-2 data
        float*       __restrict__ gS = ws + bS * 4 * G3;   // SoA base (write)
        const float* __restrict__ gG = ws + bG * 4 * G3;   // SoA base (gather)
        float*       __restrict__ gZ = ws + bZ * 4 * G3;   // SoA base (zero)
        const int fc = p % SPF;
        float* const outF = (fc == SPF - 1) ? (out + (p / SPF) * G3) : nullptr;

        // grown scatter tile = prev true bbox +1 cell each side (fast path;
        // per-substep motion < 0.15 cells -> no bbox sync needed)
        const int tmn0 = pvalid ? maxi(pmn0 - 1, 0) : 0;
        const int tmn1 = pvalid ? maxi(pmn1 - 1, 0) : 0;
        const int tmn2 = pvalid ? maxi(pmn2 - 1, 0) : 0;
        const int tD0  = pvalid ? (mini(pmx0 + 1, G - 1) - tmn0 + 1) : 0;
        const int tD1  = pvalid ? (mini(pmx1 + 1, G - 1) - tmn1 + 1) : 0;
        const int tD2  = pvalid ? (mini(pmx2 + 1, G - 1) - tmn2 + 1) : 0;
        const int tvol = pvalid ? tD0 * tD1 * tD2 : 0;
        const bool fast = pvalid && (tvol <= TCOUT);

        // ---- [pre-S1] staging FIRST: loads go in flight, everything below
        // (pure stores / LDS zeroing) overlaps their MALL latency ----
        const int iD1 = pvalid ? (pmx1 - pmn1 + 1) : 0;
        const int iD2 = pvalid ? (pmx2 - pmn2 + 1) : 0;
        const int inVol = pvalid ? (pmx0 - pmn0 + 1) * iD1 * iD2 : 0;
        const bool staged = pvalid && (inVol <= TCIN);
        if (staged) {
            for (int c = threadIdx.x; c < inVol; c += NTHR) {
                const int k = c % iD2;
                const int t = c / iD2;
                const int j = t % iD1;
                const int i = t / iD1;
                const int nx = pmn0 + i, ny = pmn1 + j, nz = pmn2 + k;
                const int gidx = (nx * G + ny) * G + nz;
                const float qx = fload_ag(gG + gidx);
                const float qy = fload_ag(gG + G3 + gidx);
                const float qz = fload_ag(gG + 2 * G3 + gidx);
                const float qm = fload_ag(gG + 3 * G3 + gidx);
                const float den = qm + vs;
                float gvx = qx / den;
                float gvy = qy / den;
                float gvz = qz / den;
                if (nx < 3       && gvx < 0.f) gvx = 0.f;
                if (nx >= G - 3  && gvx > 0.f) gvx = 0.f;
                if (ny < 3       && gvy < 0.f) gvy = 0.f;
                if (ny >= G - 3  && gvy > 0.f) gvy = 0.f;
                if (nz < 3       && gvz < 0.f) gvz = 0.f;
                if (nz >= G - 3  && gvz > 0.f) gvz = 0.f;
                tileIn[c] = make_float4(gvx, gvy, gvz, 0.f);
            }
        }
        // tileOut zero (grown tile in fast path, full capacity in fallback)
        {
            float4* t4 = reinterpret_cast<float4*>(tileOut);
            const float4 z = make_float4(0.f, 0.f, 0.f, 0.f);
            const int zn = fast ? tvol : TCOUT;
            for (int i = threadIdx.x; i < zn; i += NTHR) t4[i] = z;
        }
        // zero substep p-2's per-wg TRUE bbox (plain MALL stores; r8 showed
        // hot-line plain stores are ~free -- only RMW atomics serialize)
        if (zvalid) {
            const int zD1 = zmx1 - zmn1 + 1, zD2 = zmx2 - zmn2 + 1;
            const int zvol = (zmx0 - zmn0 + 1) * zD1 * zD2;
            for (int c = threadIdx.x; c < zvol; c += NTHR) {
                const int k = c % zD2;
                const int t = c / zD2;
                const int j = t % zD1;
                const int i = t / zD1;
                const int gidx = ((zmn0 + i) * G + (zmn1 + j)) * G + (zmn2 + k);
                fstore_ag(gZ + gidx, 0.f);
                fstore_ag(gZ + G3 + gidx, 0.f);
                fstore_ag(gZ + 2 * G3 + gidx, 0.f);
                fstore_ag(gZ + 3 * G3 + gidx, 0.f);
            }
        }
        if (threadIdx.x == 0) {
            sred[0] = INT_MAX; sred[1] = INT_MAX; sred[2] = INT_MAX;
            sred[3] = INT_MIN; sred[4] = INT_MIN; sred[5] = INT_MIN;
        }
        bar_lds();   // S1 (LDS-visibility only)

        int sb0 = 0, sb1 = 0, sb2 = 0;
        float fx0 = 0.f, fx1 = 0.f, fx2 = 0.f;
        float A00 = 0.f, A01 = 0.f, A02 = 0.f,
              A10 = 0.f, A11 = 0.f, A12 = 0.f,
              A20 = 0.f, A21 = 0.f, A22 = 0.f;
        float mvx = 0.f, mvy = 0.f, mvz = 0.f;

        if (act) {
            // ======== G2P gather for substep p-1 (cells c%4==sub per lane) ========
            if (p > 0) {
                const float xs0 = px * INV_DX, xs1 = py * INV_DX, xs2 = pz * INV_DX;
                const float fb0 = floorf(xs0 - 0.5f), fb1 = floorf(xs1 - 0.5f), fb2 = floorf(xs2 - 0.5f);
                const int b0 = (int)fb0, b1 = (int)fb1, b2 = (int)fb2;
                const float gx0 = xs0 - fb0, gx1 = xs1 - fb1, gx2 = xs2 - fb2;
                float wa[3], wb[3], wc[3];
                wa[0] = 0.5f * (1.5f - gx0) * (1.5f - gx0);
                wa[1] = 0.75f - (gx0 - 1.0f) * (gx0 - 1.0f);
                wa[2] = 0.5f * (gx0 - 0.5f) * (gx0 - 0.5f);
                wb[0] = 0.5f * (1.5f - gx1) * (1.5f - gx1);
                wb[1] = 0.75f - (gx1 - 1.0f) * (gx1 - 1.0f);
                wb[2] = 0.5f * (gx1 - 0.5f) * (gx1 - 0.5f);
                wc[0] = 0.5f * (1.5f - gx2) * (1.5f - gx2);
                wc[1] = 0.75f - (gx2 - 1.0f) * (gx2 - 1.0f);
                wc[2] = 0.5f * (gx2 - 0.5f) * (gx2 - 0.5f);

                float nvx = 0.f, nvy = 0.f, nvz = 0.f;
                float nc00 = 0.f, nc01 = 0.f, nc02 = 0.f,
                      nc10 = 0.f, nc11 = 0.f, nc12 = 0.f,
                      nc20 = 0.f, nc21 = 0.f, nc22 = 0.f;
                #pragma unroll
                for (int t = 0; t < 7; ++t) {
                    const int c = sub + 4 * t;
                    if (c >= 27) break;
                    const int oi = c / 9;
                    const int rem = c - 9 * oi;
                    const int oj = rem / 3;
                    const int ok = rem - 3 * oj;
                    const int nx = clampi(b0 + oi);
                    const int ny = clampi(b1 + oj);
                    const int nz = clampi(b2 + ok);
                    const float dpx = ((float)oi - gx0) * DXc;
                    const float dpy = ((float)oj - gx1) * DXc;
                    const float dpz = ((float)ok - gx2) * DXc;
                    const float w = wa[oi] * wb[oj] * wc[ok];
                    float gvx, gvy, gvz;
                    if (staged) {
                        const float4 gv4 = tileIn[((nx - pmn0) * iD1 + (ny - pmn1)) * iD2 + (nz - pmn2)];
                        gvx = gv4.x; gvy = gv4.y; gvz = gv4.z;
                    } else {
                        const int gidx = (nx * G + ny) * G + nz;
                        const float qx = fload_ag(gG + gidx);
                        const float qy = fload_ag(gG + G3 + gidx);
                        const float qz = fload_ag(gG + 2 * G3 + gidx);
                        const float qm = fload_ag(gG + 3 * G3 + gidx);
                        const float den = qm + vs;
                        gvx = qx / den;
                        gvy = qy / den;
                        gvz = qz / den;
                        if (nx < 3       && gvx < 0.f) gvx = 0.f;
                        if (nx >= G - 3  && gvx > 0.f) gvx = 0.f;
                        if (ny < 3       && gvy < 0.f) gvy = 0.f;
                        if (ny >= G - 3  && gvy > 0.f) gvy = 0.f;
                        if (nz < 3       && gvz < 0.f) gvz = 0.f;
                        if (nz >= G - 3  && gvz > 0.f) gvz = 0.f;
                    }
                    nvx += w * gvx; nvy += w * gvy; nvz += w * gvz;
                    const float wgx = w * gvx, wgy = w * gvy, wgz = w * gvz;
                    nc00 += wgx * dpx; nc01 += wgx * dpy; nc02 += wgx * dpz;
                    nc10 += wgy * dpx; nc11 += wgy * dpy; nc12 += wgy * dpz;
                    nc20 += wgz * dpx; nc21 += wgz * dpy; nc22 += wgz * dpz;
                }
                // 4-lane butterfly: all lanes end with identical full sums
                #define BFLY(v) { v += __shfl_xor(v, 1); v += __shfl_xor(v, 2); }
                BFLY(nvx) BFLY(nvy) BFLY(nvz)
                BFLY(nc00) BFLY(nc01) BFLY(nc02)
                BFLY(nc10) BFLY(nc11) BFLY(nc12)
                BFLY(nc20) BFLY(nc21) BFLY(nc22)
                #undef BFLY
                vx = nvx; vy = nvy; vz = nvz;
                C00 = CSC * nc00; C01 = CSC * nc01; C02 = CSC * nc02;
                C10 = CSC * nc10; C11 = CSC * nc11; C12 = CSC * nc12;
                C20 = CSC * nc20; C21 = CSC * nc21; C22 = CSC * nc22;
                px += DT * vx; py += DT * vy; pz += DT * vz;
            }

            // ======== F update: F = (I + DT*C) @ F (replicated) ========
            {
                const float t00 = F00 + DT * (C00 * F00 + C01 * F10 + C02 * F20);
                const float t01 = F01 + DT * (C00 * F01 + C01 * F11 + C02 * F21);
                const float t02 = F02 + DT * (C00 * F02 + C01 * F12 + C02 * F22);
                const float t10 = F10 + DT * (C10 * F00 + C11 * F10 + C12 * F20);
                const float t11 = F11 + DT * (C10 * F01 + C11 * F11 + C12 * F21);
                const float t12 = F12 + DT * (C10 * F02 + C11 * F12 + C12 * F22);
                const float t20 = F20 + DT * (C20 * F00 + C21 * F10 + C22 * F20);
                const float t21 = F21 + DT * (C20 * F01 + C21 * F11 + C22 * F21);
                const float t22 = F22 + DT * (C20 * F02 + C21 * F12 + C22 * F22);
                F00 = t00; F01 = t01; F02 = t02;
                F10 = t10; F11 = t11; F12 = t12;
                F20 = t20; F21 = t21; F22 = t22;
            }

            // ======== neo-Hookean PK1 stress -> affine (replicated) ========
            const float c00 = F11 * F22 - F12 * F21;
            const float c01 = F12 * F20 - F10 * F22;
            const float c02 = F10 * F21 - F11 * F20;
            const float det = F00 * c00 + F01 * c01 + F02 * c02;
            const float c10 = F02 * F21 - F01 * F22;
            const float c11 = F00 * F22 - F02 * F20;
            const float c12 = F01 * F20 - F00 * F21;
            const float c20 = F01 * F12 - F02 * F11;
            const float c21 = F02 * F10 - F00 * F12;
            const float c22 = F00 * F11 - F01 * F10;
            const float idet = 1.0f / det;
            const float lj = LAM * logf(fmaxf(det, 1e-6f));
            const float fit00 = c00 * idet, fit01 = c01 * idet, fit02 = c02 * idet;
            const float fit10 = c10 * idet, fit11 = c11 * idet, fit12 = c12 * idet;
            const float fit20 = c20 * idet, fit21 = c21 * idet, fit22 = c22 * idet;
            const float P00 = MU * (F00 - fit00) + lj * fit00;
            const float P01 = MU * (F01 - fit01) + lj * fit01;
            const float P02 = MU * (F02 - fit02) + lj * fit02;
            const float P10 = MU * (F10 - fit10) + lj * fit10;
            const float P11 = MU * (F11 - fit11) + lj * fit11;
            const float P12 = MU * (F12 - fit12) + lj * fit12;
            const float P20 = MU * (F20 - fit20) + lj * fit20;
            const float P21 = MU * (F21 - fit21) + lj * fit21;
            const float P22 = MU * (F22 - fit22) + lj * fit22;
            A00 = KS * (P00 * F00 + P01 * F01 + P02 * F02) + P_MASS * C00;
            A01 = KS * (P00 * F10 + P01 * F11 + P02 * F12) + P_MASS * C01;
            A02 = KS * (P00 * F20 + P01 * F21 + P02 * F22) + P_MASS * C02;
            A10 = KS * (P10 * F00 + P11 * F01 + P12 * F02) + P_MASS * C10;
            A11 = KS * (P10 * F10 + P11 * F11 + P12 * F12) + P_MASS * C11;
            A12 = KS * (P10 * F20 + P11 * F21 + P12 * F22) + P_MASS * C12;
            A20 = KS * (P20 * F00 + P21 * F01 + P22 * F02) + P_MASS * C20;
            A21 = KS * (P20 * F10 + P21 * F11 + P22 * F12) + P_MASS * C21;
            A22 = KS * (P20 * F20 + P21 * F21 + P22 * F22) + P_MASS * C22;

            // scatter base (from updated x)
            const float xs0 = px * INV_DX, xs1 = py * INV_DX, xs2 = pz * INV_DX;
            const float fb0 = floorf(xs0 - 0.5f), fb1 = floorf(xs1 - 0.5f), fb2 = floorf(xs2 - 0.5f);
            sb0 = (int)fb0; sb1 = (int)fb1; sb2 = (int)fb2;
            fx0 = xs0 - fb0; fx1 = xs1 - fb1; fx2 = xs2 - fb2;
            mvx = P_MASS * vx;
            mvy = P_MASS * (vy + DTG);
            mvz = P_MASS * vz;

            if (sub == 0) {   // true-bbox reduction (read only after S3)
                atomicMin(&sred[0], clampi(sb0)); atomicMax(&sred[3], clampi(sb0 + 2));
                atomicMin(&sred[1], clampi(sb1)); atomicMax(&sred[4], clampi(sb1 + 2));
                atomicMin(&sred[2], clampi(sb2)); atomicMax(&sred[5], clampi(sb2 + 2));
            }
        }

        // weights for scatter (replicated per lane group)
        float wa0 = 0.f, wa1 = 0.f, wa2 = 0.f, wb0 = 0.f, wb1 = 0.f, wb2 = 0.f,
              wcc0 = 0.f, wcc1 = 0.f, wcc2 = 0.f;
        if (act) {
            wa0 = 0.5f * (1.5f - fx0) * (1.5f - fx0);
            wa1 = 0.75f - (fx0 - 1.0f) * (fx0 - 1.0f);
            wa2 = 0.5f * (fx0 - 0.5f) * (fx0 - 0.5f);
            wb0 = 0.5f * (1.5f - fx1) * (1.5f - fx1);
            wb1 = 0.75f - (fx1 - 1.0f) * (fx1 - 1.0f);
            wb2 = 0.5f * (fx1 - 0.5f) * (fx1 - 0.5f);
            wcc0 = 0.5f * (1.5f - fx2) * (1.5f - fx2);
            wcc1 = 0.75f - (fx2 - 1.0f) * (fx2 - 1.0f);
            wcc2 = 0.5f * (fx2 - 0.5f) * (fx2 - 0.5f);
        }
        const float WA[3] = { wa0, wa1, wa2 };
        const float WB[3] = { wb0, wb1, wb2 };
        const float WC[3] = { wcc0, wcc1, wcc2 };

        if (fast) {
            // ======== scatter into grown tile, no bbox sync needed ========
            if (act) {
                #pragma unroll
                for (int t = 0; t < 7; ++t) {
                    const int c = sub + 4 * t;
                    if (c >= 27) break;
                    const int oi = c / 9;
                    const int rem = c - 9 * oi;
                    const int oj = rem / 3;
                    const int ok = rem - 3 * oj;
                    const int li  = clampi(sb0 + oi) - tmn0;
                    const int lj2 = clampi(sb1 + oj) - tmn1;
                    const int lk  = clampi(sb2 + ok) - tmn2;
                    const float dpx = ((float)oi - fx0) * DXc;
                    const float dpy = ((float)oj - fx1) * DXc;
                    const float dpz = ((float)ok - fx2) * DXc;
                    const float w = WA[oi] * WB[oj] * WC[ok];
                    const int c4 = 4 * ((li * tD1 + lj2) * tD2 + lk);
                    atomicAdd(&tileOut[c4 + 0], w * (mvx + A00 * dpx + A01 * dpy + A02 * dpz));
                    atomicAdd(&tileOut[c4 + 1], w * (mvy + A10 * dpx + A11 * dpy + A12 * dpz));
                    atomicAdd(&tileOut[c4 + 2], w * (mvz + A20 * dpx + A21 * dpy + A22 * dpz));
                    atomicAdd(&tileOut[c4 + 3], w * P_MASS);
                }
            }
            bar_lds();   // S3 (LDS-visibility only)
            // flush grown tile -> grid (agent atomics, SoA planes), skip empty
            for (int c = threadIdx.x; c < tvol; c += NTHR) {
                const float m = tileOut[4 * c + 3];
                if (m != 0.f) {
                    const int k = c % tD2;
                    const int t = c / tD2;
                    const int j = t % tD1;
                    const int i = t / tD1;
                    const int gidx = ((tmn0 + i) * G + (tmn1 + j)) * G + (tmn2 + k);
                    unsafeAtomicAdd(gS + gidx,          tileOut[4 * c + 0]);
                    unsafeAtomicAdd(gS + G3 + gidx,     tileOut[4 * c + 1]);
                    unsafeAtomicAdd(gS + 2 * G3 + gidx, tileOut[4 * c + 2]);
                    unsafeAtomicAdd(gS + 3 * G3 + gidx, m);
                    if (outF) unsafeAtomicAdd(&outF[gidx], m);
                }
            }
        } else {
            // ======== fallback: bbox-sync path (p==0 or oversized tile) ========
            bar_lds();   // S2: bbox ready (LDS-visibility only)
            const int mn0 = sred[0], mn1 = sred[1], mn2 = sred[2];
            const int mx0 = sred[3], mx1 = sred[4], mx2 = sred[5];
            const bool anyAct = (mx0 >= mn0);
            const int D1 = mx1 - mn1 + 1, D2 = mx2 - mn2 + 1;
            const int vol = anyAct ? (mx0 - mn0 + 1) * D1 * D2 : 0;
            const bool useLDS = anyAct && (vol <= TCOUT);
            if (useLDS) {
                if (act) {
                    #pragma unroll
                    for (int t = 0; t < 7; ++t) {
                        const int c = sub + 4 * t;
                        if (c >= 27) break;
                        const int oi = c / 9;
                        const int rem = c - 9 * oi;
                        const int oj = rem / 3;
                        const int ok = rem - 3 * oj;
                        const int li  = clampi(sb0 + oi) - mn0;
                        const int lj2 = clampi(sb1 + oj) - mn1;
                        const int lk  = clampi(sb2 + ok) - mn2;
                        const float dpx = ((float)oi - fx0) * DXc;
                        const float dpy = ((float)oj - fx1) * DXc;
                        const float dpz = ((float)ok - fx2) * DXc;
                        const float w = WA[oi] * WB[oj] * WC[ok];
                        const int c4 = 4 * ((li * D1 + lj2) * D2 + lk);
                        atomicAdd(&tileOut[c4 + 0], w * (mvx + A00 * dpx + A01 * dpy + A02 * dpz));
                        atomicAdd(&tileOut[c4 + 1], w * (mvy + A10 * dpx + A11 * dpy + A12 * dpz));
                        atomicAdd(&tileOut[c4 + 2], w * (mvz + A20 * dpx + A21 * dpy + A22 * dpz));
                        atomicAdd(&tileOut[c4 + 3], w * P_MASS);
                    }
                }
                bar_lds();   // S3
                for (int c = threadIdx.x; c < vol; c += NTHR) {
                    const float m = tileOut[4 * c + 3];
                    if (m != 0.f) {
                        const int k = c % D2;
                        const int t = c / D2;
                        const int j = t % D1;
                        const int i = t / D1;
                        const int gidx = ((mn0 + i) * G + (mn1 + j)) * G + (mn2 + k);
                        unsafeAtomicAdd(gS + gidx,          tileOut[4 * c + 0]);
                        unsafeAtomicAdd(gS + G3 + gidx,     tileOut[4 * c + 1]);
                        unsafeAtomicAdd(gS + 2 * G3 + gidx, tileOut[4 * c + 2]);
                        unsafeAtomicAdd(gS + 3 * G3 + gidx, m);
                        if (outF) unsafeAtomicAdd(&outF[gidx], m);
                    }
                }
            } else {
                if (anyAct && act) {
                    #pragma unroll
                    for (int t = 0; t < 7; ++t) {
                        const int c = sub + 4 * t;
                        if (c >= 27) break;
                        const int oi = c / 9;
                        const int rem = c - 9 * oi;
                        const int oj = rem / 3;
                        const int ok = rem - 3 * oj;
                        const int nx = clampi(sb0 + oi);
                        const int ny = clampi(sb1 + oj);
                        const int nz = clampi(sb2 + ok);
                        const float dpx = ((float)oi - fx0) * DXc;
                        const float dpy = ((float)oj - fx1) * DXc;
                        const float dpz = ((float)ok - fx2) * DXc;
                        const float w = WA[oi] * WB[oj] * WC[ok];
                        const int gidx = (nx * G + ny) * G + nz;
                        unsafeAtomicAdd(gS + gidx,          w * (mvx + A00 * dpx + A01 * dpy + A02 * dpz));
                        unsafeAtomicAdd(gS + G3 + gidx,     w * (mvy + A10 * dpx + A11 * dpy + A12 * dpz));
                        unsafeAtomicAdd(gS + 2 * G3 + gidx, w * (mvz + A20 * dpx + A21 * dpy + A22 * dpz));
                        unsafeAtomicAdd(gS + 3 * G3 + gidx, w * P_MASS);
                        if (outF) unsafeAtomicAdd(&outF[gidx], w * P_MASS);
                    }
                }
                bar_lds();   // S3 (uniform)
            }
        }

        // shift TRUE bbox history (sred result valid after S3)
        zmn0 = pmn0; zmn1 = pmn1; zmn2 = pmn2;
        zmx0 = pmx0; zmx1 = pmx1; zmx2 = pmx2; zvalid = pvalid;
        pmn0 = sred[0]; pmn1 = sred[1]; pmn2 = sred[2];
        pmx0 = sred[3]; pmx1 = sred[4]; pmx2 = sred[5]; pvalid = (pmx0 >= pmn0);

        if (p < NSUB - 1) {
            // ---- grid barrier: full __syncthreads (vmcnt drain publishes all
            // flush/zero stores), thread 0 is the sole global poller, LDS-flag
            // broadcast to the other waves ----
            ++gen;
            __syncthreads();
            if (threadIdx.x == 0) {
                const unsigned old = __hip_atomic_fetch_add(barcnt, 1u, __ATOMIC_RELAXED, __HIP_MEMORY_SCOPE_AGENT);
                if (old == gen * (unsigned)NBLK - 1u) {
                    __hip_atomic_store(barflag, gen, __ATOMIC_RELEASE, __HIP_MEMORY_SCOPE_AGENT);
                }
                while (__hip_atomic_load(barflag, __ATOMIC_RELAXED, __HIP_MEMORY_SCOPE_AGENT) < gen) { }
                __hip_atomic_store(&lflag, gen, __ATOMIC_RELAXED, __HIP_MEMORY_SCOPE_WORKGROUP);
            }
            while (__hip_atomic_load(&lflag, __ATOMIC_RELAXED, __HIP_MEMORY_SCOPE_WORKGROUP) < gen) { }
            asm volatile("" ::: "memory");
        }
        // last phase: kernel-end implicit release publishes the final out adds
    }
}

extern "C" void kernel_launch(void* const* d_in, const int* in_sizes, int n_in,
                              void* d_out, int out_size, void* d_ws, size_t ws_size,
                              hipStream_t stream) {
    const float* v  = (const float*)d_in[0];
    const float* q  = (const float*)d_in[1];
    const float* qd = (const float*)d_in[2];
    float* out = (float*)d_out;
    float* ws  = (float*)d_ws;
    // barrier lines at the tail of the workspace, separate 256B lines so the
    // poll stream never contests ownership of the arrival line
    char* tail = (char*)d_ws + (ws_size & ~(size_t)255);
    unsigned* barcnt  = reinterpret_cast<unsigned*>(tail - 256);
    unsigned* barflag = reinterpret_cast<unsigned*>(tail - 512);
    void* args[] = { (void*)&v, (void*)&q, (void*)&qd, (void*)&out, (void*)&ws,
                     (void*)&barcnt, (void*)&barflag };
    hipLaunchCooperativeKernel(reinterpret_cast<void*>(mpm_sim),
                               dim3(NBLK), dim3(NTHR), args, 0, stream);
}